// Round 2
// baseline (2011.398 us; speedup 1.0000x reference)
//
#include <hip/hip_runtime.h>
#include <hip/hip_bf16.h>
#include <math.h>

constexpr int IN_F = 768;
constexpr int HIDC = 128;
constexpr int HEADS = 4;
constexpr float NEG_SLOPE = 0.2f;
constexpr float BN_EPS = 1e-5f;

// ---------------- CSR build ----------------

__global__ void init_counts(int* __restrict__ count, int* __restrict__ cursor, int N) {
    int i = blockIdx.x * blockDim.x + threadIdx.x;
    if (i < N) { count[i] = 1; cursor[i] = 0; }  // count starts at 1: self-loop
}

__global__ void count_edges(const int* __restrict__ dst, int E, int* __restrict__ count) {
    int e = blockIdx.x * blockDim.x + threadIdx.x;
    if (e < E) atomicAdd(&count[dst[e]], 1);
}

// single block of 1024 threads, 4 elements/thread per chunk
__global__ void scan_counts(const int* __restrict__ count, int* __restrict__ row_start, int N) {
    __shared__ int wsum[17];
    __shared__ int carry;
    int tid = threadIdx.x;
    int lane = tid & 63, w = tid >> 6;
    if (tid == 0) carry = 0;
    __syncthreads();
    for (int base = 0; base < N; base += 4096) {
        int idx = base + tid * 4;
        int v0 = (idx + 0 < N) ? count[idx + 0] : 0;
        int v1 = (idx + 1 < N) ? count[idx + 1] : 0;
        int v2 = (idx + 2 < N) ? count[idx + 2] : 0;
        int v3 = (idx + 3 < N) ? count[idx + 3] : 0;
        int tsum = v0 + v1 + v2 + v3;
        int x = tsum;
        #pragma unroll
        for (int off = 1; off < 64; off <<= 1) {
            int y = __shfl_up(x, off, 64);
            if (lane >= off) x += y;
        }
        if (lane == 63) wsum[w] = x;
        __syncthreads();
        if (tid == 0) {
            int r = 0;
            for (int i = 0; i < 16; i++) { int t = wsum[i]; wsum[i] = r; r += t; }
            wsum[16] = r;
        }
        __syncthreads();
        int excl = carry + wsum[w] + (x - tsum);
        if (idx + 0 < N) row_start[idx + 0] = excl;
        if (idx + 1 < N) row_start[idx + 1] = excl + v0;
        if (idx + 2 < N) row_start[idx + 2] = excl + v0 + v1;
        if (idx + 3 < N) row_start[idx + 3] = excl + v0 + v1 + v2;
        __syncthreads();
        if (tid == 0) carry += wsum[16];
        __syncthreads();
    }
    if (tid == 0) row_start[N] = carry;
}

__global__ void scatter_edges(const int* __restrict__ srcA, const int* __restrict__ dstA,
                              int E, int N, const int* __restrict__ row_start,
                              int* __restrict__ cursor, int* __restrict__ col) {
    int i = blockIdx.x * blockDim.x + threadIdx.x;
    if (i < E) {
        int d = dstA[i];
        int pos = row_start[d] + atomicAdd(&cursor[d], 1);
        col[pos] = srcA[i];
    } else if (i < E + N) {
        int n = i - E;
        int pos = row_start[n] + atomicAdd(&cursor[n], 1);
        col[pos] = n;  // self loop
    }
}

// ---------------- fp32 tiled GEMM: C[M,N] = A[M,K] @ B[K,N] ----------------

__global__ __launch_bounds__(256) void gemm_tile(const float* __restrict__ A,
                                                 const float* __restrict__ B,
                                                 float* __restrict__ C,
                                                 int M, int N, int K) {
    __shared__ float As[16][68];  // row stride 272B = multiple of 16B -> aligned float4
    __shared__ float Bs[16][64];
    int tid = threadIdx.x;
    int tx = tid & 15, ty = tid >> 4;
    int row0 = blockIdx.x * 64, col0 = blockIdx.y * 64;
    float acc[4][4] = {};
    int ar = tid >> 2;          // 0..63
    int ak = (tid & 3) * 4;     // 0,4,8,12
    int bk = tid >> 4;          // 0..15
    int bc4 = (tid & 15) * 4;   // 0..60

    for (int k0 = 0; k0 < K; k0 += 16) {
        float4 av = make_float4(0.f, 0.f, 0.f, 0.f);
        int arow = row0 + ar;
        if (arow < M) av = *(const float4*)&A[(size_t)arow * K + k0 + ak];
        As[ak + 0][ar] = av.x; As[ak + 1][ar] = av.y;
        As[ak + 2][ar] = av.z; As[ak + 3][ar] = av.w;
        float4 bv = *(const float4*)&B[(size_t)(k0 + bk) * N + col0 + bc4];
        *(float4*)&Bs[bk][bc4] = bv;
        __syncthreads();
        #pragma unroll
        for (int kk = 0; kk < 16; kk++) {
            float4 a4 = *(const float4*)&As[kk][ty * 4];
            float4 b4 = *(const float4*)&Bs[kk][tx * 4];
            float aa[4] = {a4.x, a4.y, a4.z, a4.w};
            float bb[4] = {b4.x, b4.y, b4.z, b4.w};
            #pragma unroll
            for (int i = 0; i < 4; i++)
                #pragma unroll
                for (int j = 0; j < 4; j++)
                    acc[i][j] += aa[i] * bb[j];
        }
        __syncthreads();
    }
    #pragma unroll
    for (int i = 0; i < 4; i++) {
        int r = row0 + ty * 4 + i;
        if (r < M) {
            #pragma unroll
            for (int j = 0; j < 4; j++)
                C[(size_t)r * N + col0 + tx * 4 + j] = acc[i][j];
        }
    }
}

// ---------------- per-node attention scores s,d ----------------

template <int H, int C>
__global__ void node_scores(const float* __restrict__ h, const float* __restrict__ a_s,
                            const float* __restrict__ a_d, float* __restrict__ s,
                            float* __restrict__ d, int N) {
    int lane = threadIdx.x & 63;
    int w = threadIdx.x >> 6;
    int n = blockIdx.x * 4 + w;
    if (n >= N) return;
    const float* hp = h + (size_t)n * (H * C);
    #pragma unroll
    for (int hh = 0; hh < H; hh++) {
        float ps = 0.f, pd = 0.f;
        #pragma unroll
        for (int j = 0; j < C / 64; j++) {
            int c = j * 64 + lane;
            float v = hp[hh * C + c];
            ps += v * a_s[hh * C + c];
            pd += v * a_d[hh * C + c];
        }
        #pragma unroll
        for (int off = 32; off >= 1; off >>= 1) {
            ps += __shfl_xor(ps, off, 64);
            pd += __shfl_xor(pd, off, 64);
        }
        if (lane == 0) { s[n * H + hh] = ps; d[n * H + hh] = pd; }
    }
}

// ---------------- GAT aggregation (softmax over incoming edges) + bias + BN + ELU ----------------

template <int H, int C>
__global__ void gat_aggregate(const float* __restrict__ h, const float* __restrict__ s,
                              const float* __restrict__ dsc, const int* __restrict__ row_start,
                              const int* __restrict__ col, const float* __restrict__ bias,
                              const float* __restrict__ gam, const float* __restrict__ beta,
                              const float* __restrict__ rm, const float* __restrict__ rv,
                              float* __restrict__ out, int N) {
    int lane = threadIdx.x & 63;
    int w = threadIdx.x >> 6;
    int gw = blockIdx.x * 4 + w;
    int n = gw / H, hh = gw % H;
    if (n >= N) return;
    int beg = row_start[n], end = row_start[n + 1];
    float dn = dsc[n * H + hh];
    float m = -1e30f;
    for (int i = beg; i < end; i++) {
        float e = s[col[i] * H + hh] + dn;
        e = e > 0.f ? e : NEG_SLOPE * e;
        m = fmaxf(m, e);
    }
    float acc0 = 0.f, acc1 = 0.f, denom = 0.f;
    for (int i = beg; i < end; i++) {
        int sn = col[i];
        float e = s[sn * H + hh] + dn;
        e = e > 0.f ? e : NEG_SLOPE * e;
        float wgt = __expf(e - m);
        denom += wgt;
        const float* hp = h + (size_t)sn * (H * C) + hh * C;
        acc0 += wgt * hp[lane];
        if (C > 64) acc1 += wgt * hp[64 + lane];
    }
    float inv = 1.f / denom;
    {
        int ch = hh * C + lane;
        float v = acc0 * inv + bias[ch];
        v = (v - rm[ch]) * (gam[ch] * rsqrtf(rv[ch] + BN_EPS)) + beta[ch];
        v = v > 0.f ? v : expf(v) - 1.f;
        out[(size_t)n * (H * C) + ch] = v;
    }
    if (C > 64) {
        int ch = hh * C + 64 + lane;
        float v = acc1 * inv + bias[ch];
        v = (v - rm[ch]) * (gam[ch] * rsqrtf(rv[ch] + BN_EPS)) + beta[ch];
        v = v > 0.f ? v : expf(v) - 1.f;
        out[(size_t)n * (H * C) + ch] = v;
    }
}

// ---------------- classifier: [N,128] @ [128,2] + bc -> float32 out ----------------

__global__ void classifier_k(const float* __restrict__ a, const float* __restrict__ Wc,
                             const float* __restrict__ bc, float* __restrict__ out, int N) {
    int lane = threadIdx.x & 63;
    int w = threadIdx.x >> 6;
    int n = blockIdx.x * 4 + w;
    if (n >= N) return;
    float v0 = a[(size_t)n * 128 + lane];
    float v1 = a[(size_t)n * 128 + 64 + lane];
    float p0 = v0 * Wc[lane * 2 + 0] + v1 * Wc[(64 + lane) * 2 + 0];
    float p1 = v0 * Wc[lane * 2 + 1] + v1 * Wc[(64 + lane) * 2 + 1];
    #pragma unroll
    for (int off = 32; off >= 1; off >>= 1) {
        p0 += __shfl_xor(p0, off, 64);
        p1 += __shfl_xor(p1, off, 64);
    }
    if (lane == 0) {
        out[n * 2 + 0] = p0 + bc[0];
        out[n * 2 + 1] = p1 + bc[1];
    }
}

// ---------------- launch ----------------

extern "C" void kernel_launch(void* const* d_in, const int* in_sizes, int n_in,
                              void* d_out, int out_size, void* d_ws, size_t ws_size,
                              hipStream_t stream) {
    const float* x   = (const float*)d_in[0];
    const int*   ei  = (const int*)d_in[1];
    const float* W1  = (const float*)d_in[2];
    const float* a1s = (const float*)d_in[3];
    const float* a1d = (const float*)d_in[4];
    const float* b1  = (const float*)d_in[5];
    const float* gm1 = (const float*)d_in[6];
    const float* be1 = (const float*)d_in[7];
    const float* rm1 = (const float*)d_in[8];
    const float* rv1 = (const float*)d_in[9];
    const float* W2  = (const float*)d_in[10];
    const float* a2s = (const float*)d_in[11];
    const float* a2d = (const float*)d_in[12];
    const float* b2  = (const float*)d_in[13];
    const float* gm2 = (const float*)d_in[14];
    const float* be2 = (const float*)d_in[15];
    const float* rm2 = (const float*)d_in[16];
    const float* rv2 = (const float*)d_in[17];
    const float* W3  = (const float*)d_in[18];
    const float* a3s = (const float*)d_in[19];
    const float* a3d = (const float*)d_in[20];
    const float* b3  = (const float*)d_in[21];
    const float* gm3 = (const float*)d_in[22];
    const float* be3 = (const float*)d_in[23];
    const float* rm3 = (const float*)d_in[24];
    const float* rv3 = (const float*)d_in[25];
    const float* Wc  = (const float*)d_in[26];
    const float* bc  = (const float*)d_in[27];

    int N = in_sizes[0] / IN_F;       // 50000
    int E = in_sizes[1] / 2;          // 400000
    const int* srcA = ei;             // edge_index[0]
    const int* dstA = ei + E;         // edge_index[1]
    const int OUTF = HEADS * HIDC;    // 512

    float* B0   = (float*)d_ws;                       // N*512
    float* B1   = B0 + (size_t)N * OUTF;              // N*512
    float* sbuf = B1 + (size_t)N * OUTF;              // N*4
    float* dbuf = sbuf + (size_t)N * HEADS;           // N*4
    int* count     = (int*)(dbuf + (size_t)N * HEADS);
    int* cursor    = count + N;
    int* row_start = cursor + N;
    int* col       = row_start + N + 1;               // E + N entries

    // CSR build (edge_index is constant but ws is re-poisoned: rebuild every call)
    init_counts<<<(N + 255) / 256, 256, 0, stream>>>(count, cursor, N);
    count_edges<<<(E + 255) / 256, 256, 0, stream>>>(dstA, E, count);
    scan_counts<<<1, 1024, 0, stream>>>(count, row_start, N);
    scatter_edges<<<(E + N + 255) / 256, 256, 0, stream>>>(srcA, dstA, E, N, row_start, cursor, col);

    dim3 blk(256);
    dim3 gdim1((N + 63) / 64, OUTF / 64);

    // Layer 1
    gemm_tile<<<gdim1, blk, 0, stream>>>(x, W1, B0, N, OUTF, IN_F);
    node_scores<4, 128><<<(N + 3) / 4, blk, 0, stream>>>(B0, a1s, a1d, sbuf, dbuf, N);
    gat_aggregate<4, 128><<<(N * 4 + 3) / 4, blk, 0, stream>>>(B0, sbuf, dbuf, row_start, col,
                                                               b1, gm1, be1, rm1, rv1, B1, N);
    // Layer 2
    gemm_tile<<<gdim1, blk, 0, stream>>>(B1, W2, B0, N, OUTF, OUTF);
    node_scores<4, 128><<<(N + 3) / 4, blk, 0, stream>>>(B0, a2s, a2d, sbuf, dbuf, N);
    gat_aggregate<4, 128><<<(N * 4 + 3) / 4, blk, 0, stream>>>(B0, sbuf, dbuf, row_start, col,
                                                               b2, gm2, be2, rm2, rv2, B1, N);
    // Layer 3 (1 head, 128 out)
    float* h3 = B0;                     // reuse B0[0 : N*128)
    float* o3 = B0 + (size_t)N * 128;   // B0[N*128 : 2*N*128)
    dim3 gdim3((N + 63) / 64, 128 / 64);
    gemm_tile<<<gdim3, blk, 0, stream>>>(B1, W3, h3, N, 128, OUTF);
    node_scores<1, 128><<<(N + 3) / 4, blk, 0, stream>>>(h3, a3s, a3d, sbuf, dbuf, N);
    gat_aggregate<1, 128><<<(N + 3) / 4, blk, 0, stream>>>(h3, sbuf, dbuf, row_start, col,
                                                           b3, gm3, be3, rm3, rv3, o3, N);
    // Classifier
    classifier_k<<<(N + 3) / 4, blk, 0, stream>>>(o3, Wc, bc, (float*)d_out, N);
}

// Round 3
// 989.183 us; speedup vs baseline: 2.0334x; 2.0334x over previous
//
#include <hip/hip_runtime.h>
#include <hip/hip_bf16.h>
#include <math.h>

constexpr int IN_F = 768;
constexpr float NEG_SLOPE = 0.2f;
constexpr float BN_EPS = 1e-5f;

typedef __attribute__((ext_vector_type(8))) short short8;
typedef __attribute__((ext_vector_type(4))) float f32x4;

__device__ inline float bf2f(unsigned short u) {
    unsigned int x = ((unsigned int)u) << 16;
    return __uint_as_float(x);
}
__device__ inline unsigned short f2bf(float f) {
    __hip_bfloat16 h = __float2bfloat16(f);
    return *(unsigned short*)&h;
}
__device__ inline void gload_lds16(const unsigned short* g, unsigned short* l) {
    __builtin_amdgcn_global_load_lds(
        (const __attribute__((address_space(1))) void*)g,
        (__attribute__((address_space(3))) void*)l, 16, 0, 0);
}

// ---------------- CSR build ----------------

__global__ void init_counts(int* __restrict__ count, int* __restrict__ cursor, int N) {
    int i = blockIdx.x * blockDim.x + threadIdx.x;
    if (i < N) { count[i] = 1; cursor[i] = 0; }  // self-loop included
}

__global__ void count_edges(const int* __restrict__ dst, int E, int* __restrict__ count) {
    int e = blockIdx.x * blockDim.x + threadIdx.x;
    if (e < E) atomicAdd(&count[dst[e]], 1);
}

__global__ void scan_counts(const int* __restrict__ count, int* __restrict__ row_start, int N) {
    __shared__ int wsum[17];
    __shared__ int carry;
    int tid = threadIdx.x;
    int lane = tid & 63, w = tid >> 6;
    if (tid == 0) carry = 0;
    __syncthreads();
    for (int base = 0; base < N; base += 4096) {
        int idx = base + tid * 4;
        int v0 = (idx + 0 < N) ? count[idx + 0] : 0;
        int v1 = (idx + 1 < N) ? count[idx + 1] : 0;
        int v2 = (idx + 2 < N) ? count[idx + 2] : 0;
        int v3 = (idx + 3 < N) ? count[idx + 3] : 0;
        int tsum = v0 + v1 + v2 + v3;
        int x = tsum;
        #pragma unroll
        for (int off = 1; off < 64; off <<= 1) {
            int y = __shfl_up(x, off, 64);
            if (lane >= off) x += y;
        }
        if (lane == 63) wsum[w] = x;
        __syncthreads();
        if (tid == 0) {
            int r = 0;
            for (int i = 0; i < 16; i++) { int t = wsum[i]; wsum[i] = r; r += t; }
            wsum[16] = r;
        }
        __syncthreads();
        int excl = carry + wsum[w] + (x - tsum);
        if (idx + 0 < N) row_start[idx + 0] = excl;
        if (idx + 1 < N) row_start[idx + 1] = excl + v0;
        if (idx + 2 < N) row_start[idx + 2] = excl + v0 + v1;
        if (idx + 3 < N) row_start[idx + 3] = excl + v0 + v1 + v2;
        __syncthreads();
        if (tid == 0) carry += wsum[16];
        __syncthreads();
    }
    if (tid == 0) row_start[N] = carry;
}

__global__ void scatter_edges(const int* __restrict__ srcA, const int* __restrict__ dstA,
                              int E, int N, const int* __restrict__ row_start,
                              int* __restrict__ cursor, int* __restrict__ col) {
    int i = blockIdx.x * blockDim.x + threadIdx.x;
    if (i < E) {
        int d = dstA[i];
        int pos = row_start[d] + atomicAdd(&cursor[d], 1);
        col[pos] = srcA[i];
    } else if (i < E + N) {
        int n = i - E;
        int pos = row_start[n] + atomicAdd(&cursor[n], 1);
        col[pos] = n;
    }
}

// ---------------- casts ----------------

__global__ void cast_x_bf16(const float* __restrict__ x, unsigned short* __restrict__ xb,
                            long total) {
    long i = ((long)blockIdx.x * blockDim.x + threadIdx.x) * 4;
    if (i >= total) return;
    float4 v = *(const float4*)&x[i];
    ushort2 a = make_ushort2(f2bf(v.x), f2bf(v.y));
    ushort2 b = make_ushort2(f2bf(v.z), f2bf(v.w));
    *(ushort2*)&xb[i] = a;
    *(ushort2*)&xb[i + 2] = b;
}

// W [K][Ncols] fp32 -> Wt [Ncols][K] bf16
__global__ void cast_transpose_w(const float* __restrict__ W, unsigned short* __restrict__ Wt,
                                 int K, int Ncols) {
    int idx = blockIdx.x * blockDim.x + threadIdx.x;
    if (idx >= K * Ncols) return;
    int k = idx / Ncols, n = idx % Ncols;
    Wt[(size_t)n * K + k] = f2bf(W[idx]);
}

// ---------------- bf16 MFMA GEMM: C[M,Nc] = A[M,K] @ Wt[Nc,K]^T, out bf16 ----------------
// 128x128 tile, BK=32, 4 waves (2x2), each wave 64x64 via 4x4 of 16x16x32 MFMAs.

__global__ __launch_bounds__(256) void gemm_bf16(const unsigned short* __restrict__ A,
                                                 const unsigned short* __restrict__ Wt,
                                                 unsigned short* __restrict__ C,
                                                 int M, int Nc, int K) {
    __shared__ __align__(16) unsigned short As[128 * 32];
    __shared__ __align__(16) unsigned short Bs[128 * 32];
    const int tid = threadIdx.x;
    const int lane = tid & 63;
    const int wave = tid >> 6;
    const int wm = wave >> 1, wn = wave & 1;
    const int row0 = blockIdx.x * 128, col0 = blockIdx.y * 128;

    f32x4 acc[4][4];
    #pragma unroll
    for (int i = 0; i < 4; i++)
        #pragma unroll
        for (int j = 0; j < 4; j++)
            acc[i][j] = (f32x4){0.f, 0.f, 0.f, 0.f};

    const int ldm = tid >> 2;            // 0..63
    const int kpart = (tid & 3) * 8;     // 0,8,16,24
    const int khalf = (lane >> 4) * 8;
    const int fr = lane & 15;

    for (int k0 = 0; k0 < K; k0 += 32) {
        __syncthreads();  // previous iter's ds_reads complete before overwrite
        #pragma unroll
        for (int i = 0; i < 2; i++) {
            int m = i * 64 + ldm;
            int gr = row0 + m; if (gr >= M) gr = M - 1;
            gload_lds16(A + (size_t)gr * K + k0 + kpart, &As[i * 2048 + tid * 8]);
            int n = col0 + i * 64 + ldm;
            gload_lds16(Wt + (size_t)n * K + k0 + kpart, &Bs[i * 2048 + tid * 8]);
        }
        __syncthreads();  // compiler drains vmcnt before barrier -> LDS valid
        short8 a[4], b[4];
        #pragma unroll
        for (int t = 0; t < 4; t++) {
            a[t] = *(const short8*)&As[(wm * 64 + t * 16 + fr) * 32 + khalf];
            b[t] = *(const short8*)&Bs[(wn * 64 + t * 16 + fr) * 32 + khalf];
        }
        #pragma unroll
        for (int mi = 0; mi < 4; mi++)
            #pragma unroll
            for (int ni = 0; ni < 4; ni++)
                acc[mi][ni] = __builtin_amdgcn_mfma_f32_16x16x32_bf16(
                    a[mi], b[ni], acc[mi][ni], 0, 0, 0);
    }

    // C/D layout: col = lane&15, row = (lane>>4)*4 + reg
    const int rbase = row0 + wm * 64 + (lane >> 4) * 4;
    const int cbase = col0 + wn * 64 + fr;
    #pragma unroll
    for (int mi = 0; mi < 4; mi++) {
        #pragma unroll
        for (int reg = 0; reg < 4; reg++) {
            int r = rbase + mi * 16 + reg;
            if (r < M) {
                #pragma unroll
                for (int ni = 0; ni < 4; ni++)
                    C[(size_t)r * Nc + cbase + ni * 16] = f2bf(acc[mi][ni][reg]);
            }
        }
    }
}

// ---------------- per-node attention scores (bf16 h) ----------------

template <int H>
__global__ void node_scores_bf16(const unsigned short* __restrict__ h,
                                 const float* __restrict__ a_s, const float* __restrict__ a_d,
                                 float* __restrict__ s, float* __restrict__ d, int N) {
    int lane = threadIdx.x & 63;
    int w = threadIdx.x >> 6;
    int n = blockIdx.x * 4 + w;
    if (n >= N) return;
    const unsigned short* hp = h + (size_t)n * (H * 128);
    #pragma unroll
    for (int hh = 0; hh < H; hh++) {
        int c = hh * 128 + lane * 2;
        unsigned int raw = *(const unsigned int*)&hp[c];
        float v0 = bf2f((unsigned short)(raw & 0xffff));
        float v1 = bf2f((unsigned short)(raw >> 16));
        float ps = v0 * a_s[c] + v1 * a_s[c + 1];
        float pd = v0 * a_d[c] + v1 * a_d[c + 1];
        #pragma unroll
        for (int off = 32; off >= 1; off >>= 1) {
            ps += __shfl_xor(ps, off, 64);
            pd += __shfl_xor(pd, off, 64);
        }
        if (lane == 0) { s[n * H + hh] = ps; d[n * H + hh] = pd; }
    }
}

// ---------------- GAT aggregation + bias + BN + ELU (bf16 h gather) ----------------
// no max-subtraction: scores are O(10), exp is safe in fp32, result identical.

template <int H, bool OUT_BF16>
__global__ void gat_aggregate2(const unsigned short* __restrict__ h, const float* __restrict__ s,
                               const float* __restrict__ dsc, const int* __restrict__ row_start,
                               const int* __restrict__ col, const float* __restrict__ bias,
                               const float* __restrict__ gam, const float* __restrict__ beta,
                               const float* __restrict__ rm, const float* __restrict__ rv,
                               void* __restrict__ outv, int N) {
    int lane = threadIdx.x & 63;
    int w = threadIdx.x >> 6;
    int gw = blockIdx.x * 4 + w;
    int n = (H == 1) ? gw : gw / H;
    int hh = (H == 1) ? 0 : gw % H;
    if (n >= N) return;
    int beg = row_start[n], end = row_start[n + 1];
    float dn = dsc[n * H + hh];
    float acc0 = 0.f, acc1 = 0.f, denom = 0.f;
    for (int i = beg; i < end; i++) {
        int sn = col[i];
        float e = s[sn * H + hh] + dn;
        e = e > 0.f ? e : NEG_SLOPE * e;
        float wgt = __expf(e);
        denom += wgt;
        unsigned int raw = *(const unsigned int*)&h[(size_t)sn * (H * 128) + hh * 128 + lane * 2];
        acc0 += wgt * bf2f((unsigned short)(raw & 0xffff));
        acc1 += wgt * bf2f((unsigned short)(raw >> 16));
    }
    float inv = 1.f / denom;
    int ch0 = hh * 128 + lane * 2;
    float v0 = acc0 * inv + bias[ch0];
    v0 = (v0 - rm[ch0]) * (gam[ch0] * rsqrtf(rv[ch0] + BN_EPS)) + beta[ch0];
    v0 = v0 > 0.f ? v0 : expf(v0) - 1.f;
    float v1 = acc1 * inv + bias[ch0 + 1];
    v1 = (v1 - rm[ch0 + 1]) * (gam[ch0 + 1] * rsqrtf(rv[ch0 + 1] + BN_EPS)) + beta[ch0 + 1];
    v1 = v1 > 0.f ? v1 : expf(v1) - 1.f;
    if (OUT_BF16) {
        unsigned int p = (unsigned int)f2bf(v0) | ((unsigned int)f2bf(v1) << 16);
        ((unsigned int*)outv)[((size_t)n * (H * 128) + hh * 128) / 2 + lane] = p;
    } else {
        float* o = (float*)outv + (size_t)n * (H * 128) + ch0;
        o[0] = v0; o[1] = v1;
    }
}

// ---------------- classifier: [N,128] @ [128,2] + bc -> float32 ----------------

__global__ void classifier_k(const float* __restrict__ a, const float* __restrict__ Wc,
                             const float* __restrict__ bc, float* __restrict__ out, int N) {
    int lane = threadIdx.x & 63;
    int w = threadIdx.x >> 6;
    int n = blockIdx.x * 4 + w;
    if (n >= N) return;
    float v0 = a[(size_t)n * 128 + lane];
    float v1 = a[(size_t)n * 128 + 64 + lane];
    float p0 = v0 * Wc[lane * 2 + 0] + v1 * Wc[(64 + lane) * 2 + 0];
    float p1 = v0 * Wc[lane * 2 + 1] + v1 * Wc[(64 + lane) * 2 + 1];
    #pragma unroll
    for (int off = 32; off >= 1; off >>= 1) {
        p0 += __shfl_xor(p0, off, 64);
        p1 += __shfl_xor(p1, off, 64);
    }
    if (lane == 0) {
        out[n * 2 + 0] = p0 + bc[0];
        out[n * 2 + 1] = p1 + bc[1];
    }
}

// ---------------- launch ----------------

extern "C" void kernel_launch(void* const* d_in, const int* in_sizes, int n_in,
                              void* d_out, int out_size, void* d_ws, size_t ws_size,
                              hipStream_t stream) {
    const float* x   = (const float*)d_in[0];
    const int*   ei  = (const int*)d_in[1];
    const float* W1  = (const float*)d_in[2];
    const float* a1s = (const float*)d_in[3];
    const float* a1d = (const float*)d_in[4];
    const float* b1  = (const float*)d_in[5];
    const float* gm1 = (const float*)d_in[6];
    const float* be1 = (const float*)d_in[7];
    const float* rm1 = (const float*)d_in[8];
    const float* rv1 = (const float*)d_in[9];
    const float* W2  = (const float*)d_in[10];
    const float* a2s = (const float*)d_in[11];
    const float* a2d = (const float*)d_in[12];
    const float* b2  = (const float*)d_in[13];
    const float* gm2 = (const float*)d_in[14];
    const float* be2 = (const float*)d_in[15];
    const float* rm2 = (const float*)d_in[16];
    const float* rv2 = (const float*)d_in[17];
    const float* W3  = (const float*)d_in[18];
    const float* a3s = (const float*)d_in[19];
    const float* a3d = (const float*)d_in[20];
    const float* b3  = (const float*)d_in[21];
    const float* gm3 = (const float*)d_in[22];
    const float* be3 = (const float*)d_in[23];
    const float* rm3 = (const float*)d_in[24];
    const float* rv3 = (const float*)d_in[25];
    const float* Wc  = (const float*)d_in[26];
    const float* bc  = (const float*)d_in[27];

    int N = in_sizes[0] / IN_F;       // 50000
    int E = in_sizes[1] / 2;          // 400000
    const int* srcA = ei;
    const int* dstA = ei + E;

    unsigned short* xb   = (unsigned short*)d_ws;        // N*768 bf16
    unsigned short* hbuf = xb + (size_t)N * 768;         // N*512 bf16
    unsigned short* gbuf = hbuf + (size_t)N * 512;       // N*512 bf16
    float* sbuf = (float*)(gbuf + (size_t)N * 512);      // N*4
    float* dbuf = sbuf + (size_t)N * 4;                  // N*4
    unsigned short* Wt1 = (unsigned short*)(dbuf + (size_t)N * 4);  // 512*768
    unsigned short* Wt2 = Wt1 + 512 * 768;               // 512*512
    unsigned short* Wt3 = Wt2 + 512 * 512;               // 128*512
    int* count     = (int*)(Wt3 + 128 * 512);
    int* cursor    = count + N;
    int* row_start = cursor + N;
    int* col       = row_start + N + 1;                  // E+N
    float* o3 = (float*)xb;                              // alias: xb dead after GEMM1

    // CSR (rebuild every call: ws re-poisoned)
    init_counts<<<(N + 255) / 256, 256, 0, stream>>>(count, cursor, N);
    count_edges<<<(E + 255) / 256, 256, 0, stream>>>(dstA, E, count);
    scan_counts<<<1, 1024, 0, stream>>>(count, row_start, N);
    scatter_edges<<<(E + N + 255) / 256, 256, 0, stream>>>(srcA, dstA, E, N, row_start, cursor, col);

    // casts
    long xtot = (long)N * IN_F;
    cast_x_bf16<<<(int)((xtot / 4 + 255) / 256), 256, 0, stream>>>(x, xb, xtot);
    cast_transpose_w<<<(768 * 512 + 255) / 256, 256, 0, stream>>>(W1, Wt1, 768, 512);
    cast_transpose_w<<<(512 * 512 + 255) / 256, 256, 0, stream>>>(W2, Wt2, 512, 512);
    cast_transpose_w<<<(512 * 128 + 255) / 256, 256, 0, stream>>>(W3, Wt3, 512, 128);

    int Mb = (N + 127) / 128;  // 391

    // Layer 1
    gemm_bf16<<<dim3(Mb, 4), 256, 0, stream>>>(xb, Wt1, hbuf, N, 512, 768);
    node_scores_bf16<4><<<(N + 3) / 4, 256, 0, stream>>>(hbuf, a1s, a1d, sbuf, dbuf, N);
    gat_aggregate2<4, true><<<N, 256, 0, stream>>>(hbuf, sbuf, dbuf, row_start, col,
                                                   b1, gm1, be1, rm1, rv1, gbuf, N);
    // Layer 2
    gemm_bf16<<<dim3(Mb, 4), 256, 0, stream>>>(gbuf, Wt2, hbuf, N, 512, 512);
    node_scores_bf16<4><<<(N + 3) / 4, 256, 0, stream>>>(hbuf, a2s, a2d, sbuf, dbuf, N);
    gat_aggregate2<4, true><<<N, 256, 0, stream>>>(hbuf, sbuf, dbuf, row_start, col,
                                                   b2, gm2, be2, rm2, rv2, gbuf, N);
    // Layer 3 (1 head)
    gemm_bf16<<<dim3(Mb, 1), 256, 0, stream>>>(gbuf, Wt3, hbuf, N, 128, 512);
    node_scores_bf16<1><<<(N + 3) / 4, 256, 0, stream>>>(hbuf, a3s, a3d, sbuf, dbuf, N);
    gat_aggregate2<1, false><<<(N + 3) / 4, 256, 0, stream>>>(hbuf, sbuf, dbuf, row_start, col,
                                                              b3, gm3, be3, rm3, rv3, o3, N);
    // Classifier
    classifier_k<<<(N + 3) / 4, 256, 0, stream>>>(o3, Wc, bc, (float*)d_out, N);
}

// Round 4
// 872.048 us; speedup vs baseline: 2.3065x; 1.1343x over previous
//
#include <hip/hip_runtime.h>
#include <hip/hip_bf16.h>
#include <math.h>

constexpr int IN_F = 768;
constexpr float NEG_SLOPE = 0.2f;
constexpr float BN_EPS = 1e-5f;

typedef __attribute__((ext_vector_type(8))) short short8;
typedef __attribute__((ext_vector_type(4))) float f32x4;

__device__ inline float bf2f(unsigned short u) {
    unsigned int x = ((unsigned int)u) << 16;
    return __uint_as_float(x);
}
__device__ inline unsigned short f2bf(float f) {
    __hip_bfloat16 h = __float2bfloat16(f);
    return *(unsigned short*)&h;
}
__device__ inline void gload_lds16(const unsigned short* g, unsigned short* l) {
    __builtin_amdgcn_global_load_lds(
        (const __attribute__((address_space(1))) void*)g,
        (__attribute__((address_space(3))) void*)l, 16, 0, 0);
}

// ---------------- CSR build ----------------

__global__ void init_counts(int* __restrict__ count, int* __restrict__ cursor, int N) {
    int i = blockIdx.x * blockDim.x + threadIdx.x;
    if (i < N) { count[i] = 1; cursor[i] = 0; }  // self-loop included
}

__global__ void count_edges(const int* __restrict__ dst, int E, int* __restrict__ count) {
    int e = blockIdx.x * blockDim.x + threadIdx.x;
    if (e < E) atomicAdd(&count[dst[e]], 1);
}

__global__ void scan_counts(const int* __restrict__ count, int* __restrict__ row_start, int N) {
    __shared__ int wsum[17];
    __shared__ int carry;
    int tid = threadIdx.x;
    int lane = tid & 63, w = tid >> 6;
    if (tid == 0) carry = 0;
    __syncthreads();
    for (int base = 0; base < N; base += 4096) {
        int idx = base + tid * 4;
        int v0 = (idx + 0 < N) ? count[idx + 0] : 0;
        int v1 = (idx + 1 < N) ? count[idx + 1] : 0;
        int v2 = (idx + 2 < N) ? count[idx + 2] : 0;
        int v3 = (idx + 3 < N) ? count[idx + 3] : 0;
        int tsum = v0 + v1 + v2 + v3;
        int x = tsum;
        #pragma unroll
        for (int off = 1; off < 64; off <<= 1) {
            int y = __shfl_up(x, off, 64);
            if (lane >= off) x += y;
        }
        if (lane == 63) wsum[w] = x;
        __syncthreads();
        if (tid == 0) {
            int r = 0;
            for (int i = 0; i < 16; i++) { int t = wsum[i]; wsum[i] = r; r += t; }
            wsum[16] = r;
        }
        __syncthreads();
        int excl = carry + wsum[w] + (x - tsum);
        if (idx + 0 < N) row_start[idx + 0] = excl;
        if (idx + 1 < N) row_start[idx + 1] = excl + v0;
        if (idx + 2 < N) row_start[idx + 2] = excl + v0 + v1;
        if (idx + 3 < N) row_start[idx + 3] = excl + v0 + v1 + v2;
        __syncthreads();
        if (tid == 0) carry += wsum[16];
        __syncthreads();
    }
    if (tid == 0) row_start[N] = carry;
}

__global__ void scatter_edges(const int* __restrict__ srcA, const int* __restrict__ dstA,
                              int E, int N, const int* __restrict__ row_start,
                              int* __restrict__ cursor, int* __restrict__ col,
                              int* __restrict__ dstn) {
    int i = blockIdx.x * blockDim.x + threadIdx.x;
    if (i < E) {
        int d = dstA[i];
        int pos = row_start[d] + atomicAdd(&cursor[d], 1);
        col[pos] = srcA[i];
        dstn[pos] = d;
    } else if (i < E + N) {
        int n = i - E;
        int pos = row_start[n] + atomicAdd(&cursor[n], 1);
        col[pos] = n;
        dstn[pos] = n;
    }
}

// ---------------- casts ----------------

__global__ void cast_x_bf16(const float* __restrict__ x, unsigned short* __restrict__ xb,
                            long total) {
    long i = ((long)blockIdx.x * blockDim.x + threadIdx.x) * 4;
    if (i >= total) return;
    float4 v = *(const float4*)&x[i];
    *(ushort2*)&xb[i] = make_ushort2(f2bf(v.x), f2bf(v.y));
    *(ushort2*)&xb[i + 2] = make_ushort2(f2bf(v.z), f2bf(v.w));
}

// W [K][Ncols] fp32 -> Wt [Ncols][K] bf16
__global__ void cast_transpose_w(const float* __restrict__ W, unsigned short* __restrict__ Wt,
                                 int K, int Ncols) {
    int idx = blockIdx.x * blockDim.x + threadIdx.x;
    if (idx >= K * Ncols) return;
    int k = idx / Ncols, n = idx % Ncols;
    Wt[(size_t)n * K + k] = f2bf(W[idx]);
}

// ---------------- bf16 MFMA GEMM (128x128 tile, BK=32, m97 structure) ----------------

__global__ __launch_bounds__(256) void gemm_bf16(const unsigned short* __restrict__ A,
                                                 const unsigned short* __restrict__ Wt,
                                                 unsigned short* __restrict__ C,
                                                 int M, int Nc, int K) {
    __shared__ __align__(16) unsigned short As[128 * 32];
    __shared__ __align__(16) unsigned short Bs[128 * 32];
    const int tid = threadIdx.x;
    const int lane = tid & 63;
    const int wave = tid >> 6;
    const int wm = wave >> 1, wn = wave & 1;
    const int row0 = blockIdx.x * 128, col0 = blockIdx.y * 128;

    f32x4 acc[4][4];
    #pragma unroll
    for (int i = 0; i < 4; i++)
        #pragma unroll
        for (int j = 0; j < 4; j++)
            acc[i][j] = (f32x4){0.f, 0.f, 0.f, 0.f};

    const int ldm = tid >> 2;
    const int kpart = (tid & 3) * 8;
    const int khalf = (lane >> 4) * 8;
    const int fr = lane & 15;

    for (int k0 = 0; k0 < K; k0 += 32) {
        __syncthreads();
        #pragma unroll
        for (int i = 0; i < 2; i++) {
            int gr = row0 + i * 64 + ldm; if (gr >= M) gr = M - 1;
            gload_lds16(A + (size_t)gr * K + k0 + kpart, &As[i * 2048 + tid * 8]);
            int n = col0 + i * 64 + ldm;
            gload_lds16(Wt + (size_t)n * K + k0 + kpart, &Bs[i * 2048 + tid * 8]);
        }
        __syncthreads();
        short8 a[4], b[4];
        #pragma unroll
        for (int t = 0; t < 4; t++) {
            a[t] = *(const short8*)&As[(wm * 64 + t * 16 + fr) * 32 + khalf];
            b[t] = *(const short8*)&Bs[(wn * 64 + t * 16 + fr) * 32 + khalf];
        }
        #pragma unroll
        for (int mi = 0; mi < 4; mi++)
            #pragma unroll
            for (int ni = 0; ni < 4; ni++)
                acc[mi][ni] = __builtin_amdgcn_mfma_f32_16x16x32_bf16(
                    a[mi], b[ni], acc[mi][ni], 0, 0, 0);
    }

    const int rbase = row0 + wm * 64 + (lane >> 4) * 4;
    const int cbase = col0 + wn * 64 + fr;
    #pragma unroll
    for (int mi = 0; mi < 4; mi++) {
        #pragma unroll
        for (int reg = 0; reg < 4; reg++) {
            int r = rbase + mi * 16 + reg;
            if (r < M) {
                #pragma unroll
                for (int ni = 0; ni < 4; ni++)
                    C[(size_t)r * Nc + cbase + ni * 16] = f2bf(acc[mi][ni][reg]);
            }
        }
    }
}

// ---------------- per-node attention scores ----------------

template <int H>
__global__ void node_scores_bf16(const unsigned short* __restrict__ h,
                                 const float* __restrict__ a_s, const float* __restrict__ a_d,
                                 float* __restrict__ s, float* __restrict__ d, int N) {
    int lane = threadIdx.x & 63;
    int w = threadIdx.x >> 6;
    int n = blockIdx.x * 4 + w;
    if (n >= N) return;
    const unsigned short* hp = h + (size_t)n * (H * 128);
    #pragma unroll
    for (int hh = 0; hh < H; hh++) {
        int c = hh * 128 + lane * 2;
        unsigned int raw = *(const unsigned int*)&hp[c];
        float v0 = bf2f((unsigned short)(raw & 0xffff));
        float v1 = bf2f((unsigned short)(raw >> 16));
        float ps = v0 * a_s[c] + v1 * a_s[c + 1];
        float pd = v0 * a_d[c] + v1 * a_d[c + 1];
        #pragma unroll
        for (int off = 32; off >= 1; off >>= 1) {
            ps += __shfl_xor(ps, off, 64);
            pd += __shfl_xor(pd, off, 64);
        }
        if (lane == 0) { s[n * H + hh] = ps; d[n * H + hh] = pd; }
    }
}

// ---------------- edge weights: wgt[pos][h] = exp(leaky(s[col]+d[dst])) ----------------

template <int H>
__global__ void edge_weights(const int* __restrict__ col, const int* __restrict__ dstn,
                             const float* __restrict__ s, const float* __restrict__ d,
                             float* __restrict__ wgt, int P) {
    int p = blockIdx.x * blockDim.x + threadIdx.x;
    if (p >= P) return;
    int sn = col[p], dn = dstn[p];
    if (H == 4) {
        float4 sv = *(const float4*)&s[sn * 4];
        float4 dv = *(const float4*)&d[dn * 4];
        float4 o;
        float e;
        e = sv.x + dv.x; e = e > 0.f ? e : NEG_SLOPE * e; o.x = __expf(e);
        e = sv.y + dv.y; e = e > 0.f ? e : NEG_SLOPE * e; o.y = __expf(e);
        e = sv.z + dv.z; e = e > 0.f ? e : NEG_SLOPE * e; o.z = __expf(e);
        e = sv.w + dv.w; e = e > 0.f ? e : NEG_SLOPE * e; o.w = __expf(e);
        *(float4*)&wgt[p * 4] = o;
    } else {
        float e = s[sn] + d[dn];
        e = e > 0.f ? e : NEG_SLOPE * e;
        wgt[p] = __expf(e);
    }
}

// ---------------- GAT aggregation: quarter-wave per edge, 8 gathers in flight ----------------
// wave = one (node, head); quarter q handles edge i+u*4+q; lane&15 -> 8 channels (uint4).

template <int H, bool OUT_BF16>
__global__ void gat_aggregate3(const unsigned short* __restrict__ h,
                               const float* __restrict__ wgt,
                               const int* __restrict__ row_start, const int* __restrict__ col,
                               const float* __restrict__ bias,
                               const float* __restrict__ gam, const float* __restrict__ beta,
                               const float* __restrict__ rm, const float* __restrict__ rv,
                               void* __restrict__ outv, int N) {
    int lane = threadIdx.x & 63;
    int wv = threadIdx.x >> 6;
    int gw = blockIdx.x * 4 + wv;
    int n = (H == 1) ? gw : (gw >> 2);
    int hh = (H == 1) ? 0 : (gw & 3);
    if (n >= N) return;
    int beg = row_start[n], end = row_start[n + 1];
    int q = lane >> 4;
    int fl = lane & 15;
    const size_t hoff = (size_t)hh * 128 + fl * 8;

    float acc[8] = {0.f, 0.f, 0.f, 0.f, 0.f, 0.f, 0.f, 0.f};
    float denom = 0.f;

    for (int i = beg; i < end; i += 8) {
        uint4 raw[2]; float w[2];
        #pragma unroll
        for (int u = 0; u < 2; u++) {
            int e0 = i + u * 4 + q;
            int ei = e0 < end ? e0 : end - 1;
            int sn = col[ei];
            w[u] = (e0 < end) ? wgt[ei * H + hh] : 0.f;
            raw[u] = *(const uint4*)&h[(size_t)sn * (H * 128) + hoff];
        }
        #pragma unroll
        for (int u = 0; u < 2; u++) {
            denom += w[u];
            acc[0] += w[u] * bf2f((unsigned short)(raw[u].x & 0xffff));
            acc[1] += w[u] * bf2f((unsigned short)(raw[u].x >> 16));
            acc[2] += w[u] * bf2f((unsigned short)(raw[u].y & 0xffff));
            acc[3] += w[u] * bf2f((unsigned short)(raw[u].y >> 16));
            acc[4] += w[u] * bf2f((unsigned short)(raw[u].z & 0xffff));
            acc[5] += w[u] * bf2f((unsigned short)(raw[u].z >> 16));
            acc[6] += w[u] * bf2f((unsigned short)(raw[u].w & 0xffff));
            acc[7] += w[u] * bf2f((unsigned short)(raw[u].w >> 16));
        }
    }
    #pragma unroll
    for (int c = 0; c < 8; c++) {
        acc[c] += __shfl_xor(acc[c], 16, 64);
        acc[c] += __shfl_xor(acc[c], 32, 64);
    }
    denom += __shfl_xor(denom, 16, 64);
    denom += __shfl_xor(denom, 32, 64);

    if (q == 0) {
        float inv = 1.f / denom;
        int ch0 = hh * 128 + fl * 8;
        float v[8];
        #pragma unroll
        for (int c = 0; c < 8; c++) {
            int ch = ch0 + c;
            float t = acc[c] * inv + bias[ch];
            t = (t - rm[ch]) * (gam[ch] * rsqrtf(rv[ch] + BN_EPS)) + beta[ch];
            v[c] = t > 0.f ? t : expf(t) - 1.f;
        }
        if (OUT_BF16) {
            uint4 p;
            p.x = (unsigned int)f2bf(v[0]) | ((unsigned int)f2bf(v[1]) << 16);
            p.y = (unsigned int)f2bf(v[2]) | ((unsigned int)f2bf(v[3]) << 16);
            p.z = (unsigned int)f2bf(v[4]) | ((unsigned int)f2bf(v[5]) << 16);
            p.w = (unsigned int)f2bf(v[6]) | ((unsigned int)f2bf(v[7]) << 16);
            *(uint4*)&((unsigned short*)outv)[(size_t)n * (H * 128) + ch0] = p;
        } else {
            float* o = (float*)outv + (size_t)n * (H * 128) + ch0;
            *(float4*)&o[0] = make_float4(v[0], v[1], v[2], v[3]);
            *(float4*)&o[4] = make_float4(v[4], v[5], v[6], v[7]);
        }
    }
}

// ---------------- classifier ----------------

__global__ void classifier_k(const float* __restrict__ a, const float* __restrict__ Wc,
                             const float* __restrict__ bc, float* __restrict__ out, int N) {
    int lane = threadIdx.x & 63;
    int w = threadIdx.x >> 6;
    int n = blockIdx.x * 4 + w;
    if (n >= N) return;
    float v0 = a[(size_t)n * 128 + lane];
    float v1 = a[(size_t)n * 128 + 64 + lane];
    float p0 = v0 * Wc[lane * 2 + 0] + v1 * Wc[(64 + lane) * 2 + 0];
    float p1 = v0 * Wc[lane * 2 + 1] + v1 * Wc[(64 + lane) * 2 + 1];
    #pragma unroll
    for (int off = 32; off >= 1; off >>= 1) {
        p0 += __shfl_xor(p0, off, 64);
        p1 += __shfl_xor(p1, off, 64);
    }
    if (lane == 0) {
        out[n * 2 + 0] = p0 + bc[0];
        out[n * 2 + 1] = p1 + bc[1];
    }
}

// ---------------- launch ----------------

extern "C" void kernel_launch(void* const* d_in, const int* in_sizes, int n_in,
                              void* d_out, int out_size, void* d_ws, size_t ws_size,
                              hipStream_t stream) {
    const float* x   = (const float*)d_in[0];
    const int*   ei  = (const int*)d_in[1];
    const float* W1  = (const float*)d_in[2];
    const float* a1s = (const float*)d_in[3];
    const float* a1d = (const float*)d_in[4];
    const float* b1  = (const float*)d_in[5];
    const float* gm1 = (const float*)d_in[6];
    const float* be1 = (const float*)d_in[7];
    const float* rm1 = (const float*)d_in[8];
    const float* rv1 = (const float*)d_in[9];
    const float* W2  = (const float*)d_in[10];
    const float* a2s = (const float*)d_in[11];
    const float* a2d = (const float*)d_in[12];
    const float* b2  = (const float*)d_in[13];
    const float* gm2 = (const float*)d_in[14];
    const float* be2 = (const float*)d_in[15];
    const float* rm2 = (const float*)d_in[16];
    const float* rv2 = (const float*)d_in[17];
    const float* W3  = (const float*)d_in[18];
    const float* a3s = (const float*)d_in[19];
    const float* a3d = (const float*)d_in[20];
    const float* b3  = (const float*)d_in[21];
    const float* gm3 = (const float*)d_in[22];
    const float* be3 = (const float*)d_in[23];
    const float* rm3 = (const float*)d_in[24];
    const float* rv3 = (const float*)d_in[25];
    const float* Wc  = (const float*)d_in[26];
    const float* bc  = (const float*)d_in[27];

    int N = in_sizes[0] / IN_F;       // 50000
    int E = in_sizes[1] / 2;          // 400000
    int P = E + N;                    // CSR slots
    const int* srcA = ei;
    const int* dstA = ei + E;

    unsigned short* xb   = (unsigned short*)d_ws;        // N*768 bf16
    unsigned short* hbuf = xb + (size_t)N * 768;         // N*512 bf16
    unsigned short* gbuf = hbuf + (size_t)N * 512;       // N*512 bf16
    float* sbuf = (float*)(gbuf + (size_t)N * 512);      // N*4
    float* dbuf = sbuf + (size_t)N * 4;                  // N*4
    float* wgt  = dbuf + (size_t)N * 4;                  // P*4 (16B aligned)
    unsigned short* Wt1 = (unsigned short*)(wgt + (size_t)P * 4);  // 512*768
    unsigned short* Wt2 = Wt1 + 512 * 768;               // 512*512
    unsigned short* Wt3 = Wt2 + 512 * 512;               // 128*512
    int* count     = (int*)(Wt3 + 128 * 512);
    int* cursor    = count + N;
    int* row_start = cursor + N;
    int* col       = row_start + N + 1;                  // P
    int* dstn      = col + P;                            // P
    float* o3 = (float*)xb;                              // alias: xb dead after GEMM1

    // CSR (rebuild every call: ws re-poisoned)
    init_counts<<<(N + 255) / 256, 256, 0, stream>>>(count, cursor, N);
    count_edges<<<(E + 255) / 256, 256, 0, stream>>>(dstA, E, count);
    scan_counts<<<1, 1024, 0, stream>>>(count, row_start, N);
    scatter_edges<<<(E + N + 255) / 256, 256, 0, stream>>>(srcA, dstA, E, N, row_start,
                                                           cursor, col, dstn);
    // casts
    long xtot = (long)N * IN_F;
    cast_x_bf16<<<(int)((xtot / 4 + 255) / 256), 256, 0, stream>>>(x, xb, xtot);
    cast_transpose_w<<<(768 * 512 + 255) / 256, 256, 0, stream>>>(W1, Wt1, 768, 512);
    cast_transpose_w<<<(512 * 512 + 255) / 256, 256, 0, stream>>>(W2, Wt2, 512, 512);
    cast_transpose_w<<<(512 * 128 + 255) / 256, 256, 0, stream>>>(W3, Wt3, 512, 128);

    int Mb = (N + 127) / 128;

    // Layer 1
    gemm_bf16<<<dim3(Mb, 4), 256, 0, stream>>>(xb, Wt1, hbuf, N, 512, 768);
    node_scores_bf16<4><<<(N + 3) / 4, 256, 0, stream>>>(hbuf, a1s, a1d, sbuf, dbuf, N);
    edge_weights<4><<<(P + 255) / 256, 256, 0, stream>>>(col, dstn, sbuf, dbuf, wgt, P);
    gat_aggregate3<4, true><<<N, 256, 0, stream>>>(hbuf, wgt, row_start, col,
                                                   b1, gm1, be1, rm1, rv1, gbuf, N);
    // Layer 2
    gemm_bf16<<<dim3(Mb, 4), 256, 0, stream>>>(gbuf, Wt2, hbuf, N, 512, 512);
    node_scores_bf16<4><<<(N + 3) / 4, 256, 0, stream>>>(hbuf, a2s, a2d, sbuf, dbuf, N);
    edge_weights<4><<<(P + 255) / 256, 256, 0, stream>>>(col, dstn, sbuf, dbuf, wgt, P);
    gat_aggregate3<4, true><<<N, 256, 0, stream>>>(hbuf, wgt, row_start, col,
                                                   b2, gm2, be2, rm2, rv2, gbuf, N);
    // Layer 3 (1 head)
    gemm_bf16<<<dim3(Mb, 1), 256, 0, stream>>>(gbuf, Wt3, hbuf, N, 128, 512);
    node_scores_bf16<1><<<(N + 3) / 4, 256, 0, stream>>>(hbuf, a3s, a3d, sbuf, dbuf, N);
    edge_weights<1><<<(P + 255) / 256, 256, 0, stream>>>(col, dstn, sbuf, dbuf, wgt, P);
    gat_aggregate3<1, false><<<(N + 3) / 4, 256, 0, stream>>>(hbuf, wgt, row_start, col,
                                                              b3, gm3, be3, rm3, rv3, o3, N);
    // Classifier
    classifier_k<<<(N + 3) / 4, 256, 0, stream>>>(o3, Wc, bc, (float*)d_out, N);
}

// Round 5
// 743.328 us; speedup vs baseline: 2.7059x; 1.1732x over previous
//
#include <hip/hip_runtime.h>
#include <hip/hip_bf16.h>
#include <math.h>

constexpr int IN_F = 768;
constexpr float NEG_SLOPE = 0.2f;
constexpr float BN_EPS = 1e-5f;

typedef __attribute__((ext_vector_type(8))) short short8;
typedef __attribute__((ext_vector_type(4))) float f32x4;

__device__ inline float bf2f(unsigned short u) {
    unsigned int x = ((unsigned int)u) << 16;
    return __uint_as_float(x);
}
__device__ inline unsigned short f2bf(float f) {
    __hip_bfloat16 h = __float2bfloat16(f);
    return *(unsigned short*)&h;
}
__device__ inline void gload_lds16(const unsigned short* g, unsigned short* l) {
    __builtin_amdgcn_global_load_lds(
        (const __attribute__((address_space(1))) void*)g,
        (__attribute__((address_space(3))) void*)l, 16, 0, 0);
}

// ---------------- CSR build ----------------

__global__ void init_counts(int* __restrict__ count, int* __restrict__ cursor, int N) {
    int i = blockIdx.x * blockDim.x + threadIdx.x;
    if (i < N) { count[i] = 1; cursor[i] = 0; }  // self-loop included
}

__global__ void count_edges(const int* __restrict__ dst, int E, int* __restrict__ count) {
    int e = blockIdx.x * blockDim.x + threadIdx.x;
    if (e < E) atomicAdd(&count[dst[e]], 1);
}

__global__ void scan_counts(const int* __restrict__ count, int* __restrict__ row_start, int N) {
    __shared__ int wsum[17];
    __shared__ int carry;
    int tid = threadIdx.x;
    int lane = tid & 63, w = tid >> 6;
    if (tid == 0) carry = 0;
    __syncthreads();
    for (int base = 0; base < N; base += 4096) {
        int idx = base + tid * 4;
        int v0 = (idx + 0 < N) ? count[idx + 0] : 0;
        int v1 = (idx + 1 < N) ? count[idx + 1] : 0;
        int v2 = (idx + 2 < N) ? count[idx + 2] : 0;
        int v3 = (idx + 3 < N) ? count[idx + 3] : 0;
        int tsum = v0 + v1 + v2 + v3;
        int x = tsum;
        #pragma unroll
        for (int off = 1; off < 64; off <<= 1) {
            int y = __shfl_up(x, off, 64);
            if (lane >= off) x += y;
        }
        if (lane == 63) wsum[w] = x;
        __syncthreads();
        if (tid == 0) {
            int r = 0;
            for (int i = 0; i < 16; i++) { int t = wsum[i]; wsum[i] = r; r += t; }
            wsum[16] = r;
        }
        __syncthreads();
        int excl = carry + wsum[w] + (x - tsum);
        if (idx + 0 < N) row_start[idx + 0] = excl;
        if (idx + 1 < N) row_start[idx + 1] = excl + v0;
        if (idx + 2 < N) row_start[idx + 2] = excl + v0 + v1;
        if (idx + 3 < N) row_start[idx + 3] = excl + v0 + v1 + v2;
        __syncthreads();
        if (tid == 0) carry += wsum[16];
        __syncthreads();
    }
    if (tid == 0) row_start[N] = carry;
}

__global__ void scatter_edges(const int* __restrict__ srcA, const int* __restrict__ dstA,
                              int E, int N, const int* __restrict__ row_start,
                              int* __restrict__ cursor, int* __restrict__ col,
                              int* __restrict__ dstn) {
    int i = blockIdx.x * blockDim.x + threadIdx.x;
    if (i < E) {
        int d = dstA[i];
        int pos = row_start[d] + atomicAdd(&cursor[d], 1);
        col[pos] = srcA[i];
        dstn[pos] = d;
    } else if (i < E + N) {
        int n = i - E;
        int pos = row_start[n] + atomicAdd(&cursor[n], 1);
        col[pos] = n;
        dstn[pos] = n;
    }
}

// ---------------- casts ----------------

__global__ void cast_x_bf16(const float* __restrict__ x, unsigned short* __restrict__ xb,
                            long total) {
    long i = ((long)blockIdx.x * blockDim.x + threadIdx.x) * 4;
    if (i >= total) return;
    float4 v = *(const float4*)&x[i];
    *(ushort2*)&xb[i] = make_ushort2(f2bf(v.x), f2bf(v.y));
    *(ushort2*)&xb[i + 2] = make_ushort2(f2bf(v.z), f2bf(v.w));
}

// W [K][Ncols] fp32 -> Wt [Ncols][K] bf16
__global__ void cast_transpose_w(const float* __restrict__ W, unsigned short* __restrict__ Wt,
                                 int K, int Ncols) {
    int idx = blockIdx.x * blockDim.x + threadIdx.x;
    if (idx >= K * Ncols) return;
    int k = idx / Ncols, n = idx % Ncols;
    Wt[(size_t)n * K + k] = f2bf(W[idx]);
}

// ---------------- bf16 MFMA GEMM (128x128 tile, BK=32, m97 structure) ----------------

__global__ __launch_bounds__(256) void gemm_bf16(const unsigned short* __restrict__ A,
                                                 const unsigned short* __restrict__ Wt,
                                                 unsigned short* __restrict__ C,
                                                 int M, int Nc, int K) {
    __shared__ __align__(16) unsigned short As[128 * 32];
    __shared__ __align__(16) unsigned short Bs[128 * 32];
    const int tid = threadIdx.x;
    const int lane = tid & 63;
    const int wave = tid >> 6;
    const int wm = wave >> 1, wn = wave & 1;
    const int row0 = blockIdx.x * 128, col0 = blockIdx.y * 128;

    f32x4 acc[4][4];
    #pragma unroll
    for (int i = 0; i < 4; i++)
        #pragma unroll
        for (int j = 0; j < 4; j++)
            acc[i][j] = (f32x4){0.f, 0.f, 0.f, 0.f};

    const int ldm = tid >> 2;
    const int kpart = (tid & 3) * 8;
    const int khalf = (lane >> 4) * 8;
    const int fr = lane & 15;

    for (int k0 = 0; k0 < K; k0 += 32) {
        __syncthreads();
        #pragma unroll
        for (int i = 0; i < 2; i++) {
            int gr = row0 + i * 64 + ldm; if (gr >= M) gr = M - 1;
            gload_lds16(A + (size_t)gr * K + k0 + kpart, &As[i * 2048 + tid * 8]);
            int n = col0 + i * 64 + ldm;
            gload_lds16(Wt + (size_t)n * K + k0 + kpart, &Bs[i * 2048 + tid * 8]);
        }
        __syncthreads();
        short8 a[4], b[4];
        #pragma unroll
        for (int t = 0; t < 4; t++) {
            a[t] = *(const short8*)&As[(wm * 64 + t * 16 + fr) * 32 + khalf];
            b[t] = *(const short8*)&Bs[(wn * 64 + t * 16 + fr) * 32 + khalf];
        }
        #pragma unroll
        for (int mi = 0; mi < 4; mi++)
            #pragma unroll
            for (int ni = 0; ni < 4; ni++)
                acc[mi][ni] = __builtin_amdgcn_mfma_f32_16x16x32_bf16(
                    a[mi], b[ni], acc[mi][ni], 0, 0, 0);
    }

    const int rbase = row0 + wm * 64 + (lane >> 4) * 4;
    const int cbase = col0 + wn * 64 + fr;
    #pragma unroll
    for (int mi = 0; mi < 4; mi++) {
        #pragma unroll
        for (int reg = 0; reg < 4; reg++) {
            int r = rbase + mi * 16 + reg;
            if (r < M) {
                #pragma unroll
                for (int ni = 0; ni < 4; ni++)
                    C[(size_t)r * Nc + cbase + ni * 16] = f2bf(acc[mi][ni][reg]);
            }
        }
    }
}

// ---------------- per-node attention scores (vectorized) ----------------

template <int H>
__global__ void node_scores_v(const unsigned short* __restrict__ h,
                              const float* __restrict__ a_s, const float* __restrict__ a_d,
                              float* __restrict__ s, float* __restrict__ d, int N) {
    int lane = threadIdx.x & 63;
    int wv = threadIdx.x >> 6;
    int n = blockIdx.x * 4 + wv;
    if (n >= N) return;
    if (H == 4) {
        int ch0 = lane * 8;  // covers all 512 channels; head = lane>>4
        uint4 raw = *(const uint4*)&h[(size_t)n * 512 + ch0];
        float4 as0 = *(const float4*)&a_s[ch0];
        float4 as1 = *(const float4*)&a_s[ch0 + 4];
        float4 ad0 = *(const float4*)&a_d[ch0];
        float4 ad1 = *(const float4*)&a_d[ch0 + 4];
        float v0 = bf2f((unsigned short)(raw.x & 0xffff)), v1 = bf2f((unsigned short)(raw.x >> 16));
        float v2 = bf2f((unsigned short)(raw.y & 0xffff)), v3 = bf2f((unsigned short)(raw.y >> 16));
        float v4 = bf2f((unsigned short)(raw.z & 0xffff)), v5 = bf2f((unsigned short)(raw.z >> 16));
        float v6 = bf2f((unsigned short)(raw.w & 0xffff)), v7 = bf2f((unsigned short)(raw.w >> 16));
        float ps = v0 * as0.x + v1 * as0.y + v2 * as0.z + v3 * as0.w
                 + v4 * as1.x + v5 * as1.y + v6 * as1.z + v7 * as1.w;
        float pd = v0 * ad0.x + v1 * ad0.y + v2 * ad0.z + v3 * ad0.w
                 + v4 * ad1.x + v5 * ad1.y + v6 * ad1.z + v7 * ad1.w;
        #pragma unroll
        for (int off = 8; off >= 1; off >>= 1) {
            ps += __shfl_xor(ps, off, 64);
            pd += __shfl_xor(pd, off, 64);
        }
        if ((lane & 15) == 0) {
            int hh = lane >> 4;
            s[n * 4 + hh] = ps;
            d[n * 4 + hh] = pd;
        }
    } else {
        int c = lane * 2;
        unsigned int raw = *(const unsigned int*)&h[(size_t)n * 128 + c];
        float v0 = bf2f((unsigned short)(raw & 0xffff));
        float v1 = bf2f((unsigned short)(raw >> 16));
        float ps = v0 * a_s[c] + v1 * a_s[c + 1];
        float pd = v0 * a_d[c] + v1 * a_d[c + 1];
        #pragma unroll
        for (int off = 32; off >= 1; off >>= 1) {
            ps += __shfl_xor(ps, off, 64);
            pd += __shfl_xor(pd, off, 64);
        }
        if (lane == 0) { s[n] = ps; d[n] = pd; }
    }
}

// ---------------- edge weights: wgt[pos][h] = exp(leaky(s[col]+d[dst])) ----------------

template <int H>
__global__ void edge_weights(const int* __restrict__ col, const int* __restrict__ dstn,
                             const float* __restrict__ s, const float* __restrict__ d,
                             float* __restrict__ wgt, int P) {
    int p = blockIdx.x * blockDim.x + threadIdx.x;
    if (p >= P) return;
    int sn = col[p], dn = dstn[p];
    if (H == 4) {
        float4 sv = *(const float4*)&s[sn * 4];
        float4 dv = *(const float4*)&d[dn * 4];
        float4 o;
        float e;
        e = sv.x + dv.x; e = e > 0.f ? e : NEG_SLOPE * e; o.x = __expf(e);
        e = sv.y + dv.y; e = e > 0.f ? e : NEG_SLOPE * e; o.y = __expf(e);
        e = sv.z + dv.z; e = e > 0.f ? e : NEG_SLOPE * e; o.z = __expf(e);
        e = sv.w + dv.w; e = e > 0.f ? e : NEG_SLOPE * e; o.w = __expf(e);
        *(float4*)&wgt[p * 4] = o;
    } else {
        float e = s[sn] + d[dn];
        e = e > 0.f ? e : NEG_SLOPE * e;
        wgt[p] = __expf(e);
    }
}

// ---------------- H=4 aggregation: one wave per node, full 1KB row/edge, unroll 8 ----------------
// lane owns 8 contiguous channels (head = lane>>4); denom identical across a head's lanes.

__global__ void gat_agg_h4(const unsigned short* __restrict__ h, const float* __restrict__ wgt,
                           const int* __restrict__ row_start, const int* __restrict__ col,
                           const float* __restrict__ bias,
                           const float* __restrict__ gam, const float* __restrict__ beta,
                           const float* __restrict__ rm, const float* __restrict__ rv,
                           unsigned short* __restrict__ out, int N) {
    int lane = threadIdx.x & 63;
    int wv = threadIdx.x >> 6;
    int n = blockIdx.x * 4 + wv;
    if (n >= N) return;
    int beg = row_start[n], end = row_start[n + 1];
    int hh = lane >> 4;
    int ch0 = lane * 8;

    float acc[8] = {0.f, 0.f, 0.f, 0.f, 0.f, 0.f, 0.f, 0.f};
    float denom = 0.f;

    for (int i = beg; i < end; i += 8) {
        uint4 raw[8]; float w[8];
        #pragma unroll
        for (int u = 0; u < 8; u++) {
            int e0 = i + u;
            int e = e0 < end ? e0 : end - 1;     // wave-uniform clamp; dup loads hit L1
            int sn = col[e];
            w[u] = (e0 < end) ? wgt[e * 4 + hh] : 0.f;
            raw[u] = *(const uint4*)&h[(size_t)sn * 512 + ch0];
        }
        #pragma unroll
        for (int u = 0; u < 8; u++) {
            denom += w[u];
            acc[0] += w[u] * bf2f((unsigned short)(raw[u].x & 0xffff));
            acc[1] += w[u] * bf2f((unsigned short)(raw[u].x >> 16));
            acc[2] += w[u] * bf2f((unsigned short)(raw[u].y & 0xffff));
            acc[3] += w[u] * bf2f((unsigned short)(raw[u].y >> 16));
            acc[4] += w[u] * bf2f((unsigned short)(raw[u].z & 0xffff));
            acc[5] += w[u] * bf2f((unsigned short)(raw[u].z >> 16));
            acc[6] += w[u] * bf2f((unsigned short)(raw[u].w & 0xffff));
            acc[7] += w[u] * bf2f((unsigned short)(raw[u].w >> 16));
        }
    }
    float inv = 1.f / denom;
    float v[8];
    #pragma unroll
    for (int c = 0; c < 8; c++) {
        int ch = ch0 + c;
        float t = acc[c] * inv + bias[ch];
        t = (t - rm[ch]) * (gam[ch] * rsqrtf(rv[ch] + BN_EPS)) + beta[ch];
        v[c] = t > 0.f ? t : expf(t) - 1.f;
    }
    uint4 p;
    p.x = (unsigned int)f2bf(v[0]) | ((unsigned int)f2bf(v[1]) << 16);
    p.y = (unsigned int)f2bf(v[2]) | ((unsigned int)f2bf(v[3]) << 16);
    p.z = (unsigned int)f2bf(v[4]) | ((unsigned int)f2bf(v[5]) << 16);
    p.w = (unsigned int)f2bf(v[6]) | ((unsigned int)f2bf(v[7]) << 16);
    *(uint4*)&out[(size_t)n * 512 + ch0] = p;
}

// ---------------- H=1 aggregation: quarter-wave per edge, unroll 4 (16 slots/iter) ----------------

__global__ void gat_agg_h1(const unsigned short* __restrict__ h, const float* __restrict__ wgt,
                           const int* __restrict__ row_start, const int* __restrict__ col,
                           const float* __restrict__ bias,
                           const float* __restrict__ gam, const float* __restrict__ beta,
                           const float* __restrict__ rm, const float* __restrict__ rv,
                           float* __restrict__ out, int N) {
    int lane = threadIdx.x & 63;
    int wv = threadIdx.x >> 6;
    int n = blockIdx.x * 4 + wv;
    if (n >= N) return;
    int beg = row_start[n], end = row_start[n + 1];
    int q = lane >> 4;
    int fl = lane & 15;
    const size_t hoff = fl * 8;

    float acc[8] = {0.f, 0.f, 0.f, 0.f, 0.f, 0.f, 0.f, 0.f};
    float denom = 0.f;

    for (int i = beg; i < end; i += 16) {
        uint4 raw[4]; float w[4];
        #pragma unroll
        for (int u = 0; u < 4; u++) {
            int e0 = i + u * 4 + q;
            int e = e0 < end ? e0 : end - 1;
            int sn = col[e];
            w[u] = (e0 < end) ? wgt[e] : 0.f;
            raw[u] = *(const uint4*)&h[(size_t)sn * 128 + hoff];
        }
        #pragma unroll
        for (int u = 0; u < 4; u++) {
            denom += w[u];
            acc[0] += w[u] * bf2f((unsigned short)(raw[u].x & 0xffff));
            acc[1] += w[u] * bf2f((unsigned short)(raw[u].x >> 16));
            acc[2] += w[u] * bf2f((unsigned short)(raw[u].y & 0xffff));
            acc[3] += w[u] * bf2f((unsigned short)(raw[u].y >> 16));
            acc[4] += w[u] * bf2f((unsigned short)(raw[u].z & 0xffff));
            acc[5] += w[u] * bf2f((unsigned short)(raw[u].z >> 16));
            acc[6] += w[u] * bf2f((unsigned short)(raw[u].w & 0xffff));
            acc[7] += w[u] * bf2f((unsigned short)(raw[u].w >> 16));
        }
    }
    #pragma unroll
    for (int c = 0; c < 8; c++) {
        acc[c] += __shfl_xor(acc[c], 16, 64);
        acc[c] += __shfl_xor(acc[c], 32, 64);
    }
    denom += __shfl_xor(denom, 16, 64);
    denom += __shfl_xor(denom, 32, 64);

    if (q == 0) {
        float inv = 1.f / denom;
        int ch0 = fl * 8;
        float v[8];
        #pragma unroll
        for (int c = 0; c < 8; c++) {
            int ch = ch0 + c;
            float t = acc[c] * inv + bias[ch];
            t = (t - rm[ch]) * (gam[ch] * rsqrtf(rv[ch] + BN_EPS)) + beta[ch];
            v[c] = t > 0.f ? t : expf(t) - 1.f;
        }
        float* o = out + (size_t)n * 128 + ch0;
        *(float4*)&o[0] = make_float4(v[0], v[1], v[2], v[3]);
        *(float4*)&o[4] = make_float4(v[4], v[5], v[6], v[7]);
    }
}

// ---------------- classifier ----------------

__global__ void classifier_k(const float* __restrict__ a, const float* __restrict__ Wc,
                             const float* __restrict__ bc, float* __restrict__ out, int N) {
    int lane = threadIdx.x & 63;
    int w = threadIdx.x >> 6;
    int n = blockIdx.x * 4 + w;
    if (n >= N) return;
    float v0 = a[(size_t)n * 128 + lane];
    float v1 = a[(size_t)n * 128 + 64 + lane];
    float p0 = v0 * Wc[lane * 2 + 0] + v1 * Wc[(64 + lane) * 2 + 0];
    float p1 = v0 * Wc[lane * 2 + 1] + v1 * Wc[(64 + lane) * 2 + 1];
    #pragma unroll
    for (int off = 32; off >= 1; off >>= 1) {
        p0 += __shfl_xor(p0, off, 64);
        p1 += __shfl_xor(p1, off, 64);
    }
    if (lane == 0) {
        out[n * 2 + 0] = p0 + bc[0];
        out[n * 2 + 1] = p1 + bc[1];
    }
}

// ---------------- launch ----------------

extern "C" void kernel_launch(void* const* d_in, const int* in_sizes, int n_in,
                              void* d_out, int out_size, void* d_ws, size_t ws_size,
                              hipStream_t stream) {
    const float* x   = (const float*)d_in[0];
    const int*   ei  = (const int*)d_in[1];
    const float* W1  = (const float*)d_in[2];
    const float* a1s = (const float*)d_in[3];
    const float* a1d = (const float*)d_in[4];
    const float* b1  = (const float*)d_in[5];
    const float* gm1 = (const float*)d_in[6];
    const float* be1 = (const float*)d_in[7];
    const float* rm1 = (const float*)d_in[8];
    const float* rv1 = (const float*)d_in[9];
    const float* W2  = (const float*)d_in[10];
    const float* a2s = (const float*)d_in[11];
    const float* a2d = (const float*)d_in[12];
    const float* b2  = (const float*)d_in[13];
    const float* gm2 = (const float*)d_in[14];
    const float* be2 = (const float*)d_in[15];
    const float* rm2 = (const float*)d_in[16];
    const float* rv2 = (const float*)d_in[17];
    const float* W3  = (const float*)d_in[18];
    const float* a3s = (const float*)d_in[19];
    const float* a3d = (const float*)d_in[20];
    const float* b3  = (const float*)d_in[21];
    const float* gm3 = (const float*)d_in[22];
    const float* be3 = (const float*)d_in[23];
    const float* rm3 = (const float*)d_in[24];
    const float* rv3 = (const float*)d_in[25];
    const float* Wc  = (const float*)d_in[26];
    const float* bc  = (const float*)d_in[27];

    int N = in_sizes[0] / IN_F;       // 50000
    int E = in_sizes[1] / 2;          // 400000
    int P = E + N;                    // CSR slots
    const int* srcA = ei;
    const int* dstA = ei + E;

    unsigned short* xb   = (unsigned short*)d_ws;        // N*768 bf16
    unsigned short* hbuf = xb + (size_t)N * 768;         // N*512 bf16
    unsigned short* gbuf = hbuf + (size_t)N * 512;       // N*512 bf16
    float* sbuf = (float*)(gbuf + (size_t)N * 512);      // N*4
    float* dbuf = sbuf + (size_t)N * 4;                  // N*4
    float* wgt  = dbuf + (size_t)N * 4;                  // P*4 (16B aligned)
    unsigned short* Wt1 = (unsigned short*)(wgt + (size_t)P * 4);  // 512*768
    unsigned short* Wt2 = Wt1 + 512 * 768;               // 512*512
    unsigned short* Wt3 = Wt2 + 512 * 512;               // 128*512
    int* count     = (int*)(Wt3 + 128 * 512);
    int* cursor    = count + N;
    int* row_start = cursor + N;
    int* col       = row_start + N + 1;                  // P
    int* dstn      = col + P;                            // P
    float* o3 = (float*)xb;                              // alias: xb dead after GEMM1

    // CSR (rebuild every call: ws re-poisoned)
    init_counts<<<(N + 255) / 256, 256, 0, stream>>>(count, cursor, N);
    count_edges<<<(E + 255) / 256, 256, 0, stream>>>(dstA, E, count);
    scan_counts<<<1, 1024, 0, stream>>>(count, row_start, N);
    scatter_edges<<<(E + N + 255) / 256, 256, 0, stream>>>(srcA, dstA, E, N, row_start,
                                                           cursor, col, dstn);
    // casts
    long xtot = (long)N * IN_F;
    cast_x_bf16<<<(int)((xtot / 4 + 255) / 256), 256, 0, stream>>>(x, xb, xtot);
    cast_transpose_w<<<(768 * 512 + 255) / 256, 256, 0, stream>>>(W1, Wt1, 768, 512);
    cast_transpose_w<<<(512 * 512 + 255) / 256, 256, 0, stream>>>(W2, Wt2, 512, 512);
    cast_transpose_w<<<(512 * 128 + 255) / 256, 256, 0, stream>>>(W3, Wt3, 512, 128);

    int Mb = (N + 127) / 128;
    int Nb4 = (N + 3) / 4;

    // Layer 1
    gemm_bf16<<<dim3(Mb, 4), 256, 0, stream>>>(xb, Wt1, hbuf, N, 512, 768);
    node_scores_v<4><<<Nb4, 256, 0, stream>>>(hbuf, a1s, a1d, sbuf, dbuf, N);
    edge_weights<4><<<(P + 255) / 256, 256, 0, stream>>>(col, dstn, sbuf, dbuf, wgt, P);
    gat_agg_h4<<<Nb4, 256, 0, stream>>>(hbuf, wgt, row_start, col,
                                        b1, gm1, be1, rm1, rv1, gbuf, N);
    // Layer 2
    gemm_bf16<<<dim3(Mb, 4), 256, 0, stream>>>(gbuf, Wt2, hbuf, N, 512, 512);
    node_scores_v<4><<<Nb4, 256, 0, stream>>>(hbuf, a2s, a2d, sbuf, dbuf, N);
    edge_weights<4><<<(P + 255) / 256, 256, 0, stream>>>(col, dstn, sbuf, dbuf, wgt, P);
    gat_agg_h4<<<Nb4, 256, 0, stream>>>(hbuf, wgt, row_start, col,
                                        b2, gm2, be2, rm2, rv2, gbuf, N);
    // Layer 3 (1 head)
    gemm_bf16<<<dim3(Mb, 1), 256, 0, stream>>>(gbuf, Wt3, hbuf, N, 128, 512);
    node_scores_v<1><<<Nb4, 256, 0, stream>>>(hbuf, a3s, a3d, sbuf, dbuf, N);
    edge_weights<1><<<(P + 255) / 256, 256, 0, stream>>>(col, dstn, sbuf, dbuf, wgt, P);
    gat_agg_h1<<<Nb4, 256, 0, stream>>>(hbuf, wgt, row_start, col,
                                        b3, gm3, be3, rm3, rv3, o3, N);
    // Classifier
    classifier_k<<<Nb4, 256, 0, stream>>>(o3, Wc, bc, (float*)d_out, N);
}

// Round 6
// 733.259 us; speedup vs baseline: 2.7431x; 1.0137x over previous
//
#include <hip/hip_runtime.h>
#include <hip/hip_bf16.h>
#include <math.h>

constexpr int IN_F = 768;
constexpr float NEG_SLOPE = 0.2f;
constexpr float BN_EPS = 1e-5f;

typedef __attribute__((ext_vector_type(8))) short short8;
typedef __attribute__((ext_vector_type(4))) float f32x4;

__device__ inline float bf2f(unsigned short u) {
    unsigned int x = ((unsigned int)u) << 16;
    return __uint_as_float(x);
}
__device__ inline unsigned short f2bf(float f) {
    __hip_bfloat16 h = __float2bfloat16(f);
    return *(unsigned short*)&h;
}
__device__ inline void gload_lds16(const unsigned short* g, unsigned short* l) {
    __builtin_amdgcn_global_load_lds(
        (const __attribute__((address_space(1))) void*)g,
        (__attribute__((address_space(3))) void*)l, 16, 0, 0);
}

// ---------------- CSR build ----------------

__global__ void init_counts(int* __restrict__ count, int* __restrict__ cursor, int N) {
    int i = blockIdx.x * blockDim.x + threadIdx.x;
    if (i < N) { count[i] = 1; cursor[i] = 0; }  // self-loop included
}

__global__ void count_edges(const int* __restrict__ dst, int E, int* __restrict__ count) {
    int e = blockIdx.x * blockDim.x + threadIdx.x;
    if (e < E) atomicAdd(&count[dst[e]], 1);
}

__global__ void scan_counts(const int* __restrict__ count, int* __restrict__ row_start, int N) {
    __shared__ int wsum[17];
    __shared__ int carry;
    int tid = threadIdx.x;
    int lane = tid & 63, w = tid >> 6;
    if (tid == 0) carry = 0;
    __syncthreads();
    for (int base = 0; base < N; base += 4096) {
        int idx = base + tid * 4;
        int v0 = (idx + 0 < N) ? count[idx + 0] : 0;
        int v1 = (idx + 1 < N) ? count[idx + 1] : 0;
        int v2 = (idx + 2 < N) ? count[idx + 2] : 0;
        int v3 = (idx + 3 < N) ? count[idx + 3] : 0;
        int tsum = v0 + v1 + v2 + v3;
        int x = tsum;
        #pragma unroll
        for (int off = 1; off < 64; off <<= 1) {
            int y = __shfl_up(x, off, 64);
            if (lane >= off) x += y;
        }
        if (lane == 63) wsum[w] = x;
        __syncthreads();
        if (tid == 0) {
            int r = 0;
            for (int i = 0; i < 16; i++) { int t = wsum[i]; wsum[i] = r; r += t; }
            wsum[16] = r;
        }
        __syncthreads();
        int excl = carry + wsum[w] + (x - tsum);
        if (idx + 0 < N) row_start[idx + 0] = excl;
        if (idx + 1 < N) row_start[idx + 1] = excl + v0;
        if (idx + 2 < N) row_start[idx + 2] = excl + v0 + v1;
        if (idx + 3 < N) row_start[idx + 3] = excl + v0 + v1 + v2;
        __syncthreads();
        if (tid == 0) carry += wsum[16];
        __syncthreads();
    }
    if (tid == 0) row_start[N] = carry;
}

__global__ void scatter_edges(const int* __restrict__ srcA, const int* __restrict__ dstA,
                              int E, int N, const int* __restrict__ row_start,
                              int* __restrict__ cursor, int* __restrict__ col,
                              int* __restrict__ dstn) {
    int i = blockIdx.x * blockDim.x + threadIdx.x;
    if (i < E) {
        int d = dstA[i];
        int pos = row_start[d] + atomicAdd(&cursor[d], 1);
        col[pos] = srcA[i];
        dstn[pos] = d;
    } else if (i < E + N) {
        int n = i - E;
        int pos = row_start[n] + atomicAdd(&cursor[n], 1);
        col[pos] = n;
        dstn[pos] = n;
    }
}

// ---------------- casts ----------------

__global__ void cast_x_bf16(const float* __restrict__ x, unsigned short* __restrict__ xb,
                            long total) {
    long i = ((long)blockIdx.x * blockDim.x + threadIdx.x) * 4;
    if (i >= total) return;
    float4 v = *(const float4*)&x[i];
    *(ushort2*)&xb[i] = make_ushort2(f2bf(v.x), f2bf(v.y));
    *(ushort2*)&xb[i + 2] = make_ushort2(f2bf(v.z), f2bf(v.w));
}

// W [K][Ncols] fp32 -> Wt [Ncols][K] bf16
__global__ void cast_transpose_w(const float* __restrict__ W, unsigned short* __restrict__ Wt,
                                 int K, int Ncols) {
    int idx = blockIdx.x * blockDim.x + threadIdx.x;
    if (idx >= K * Ncols) return;
    int k = idx / Ncols, n = idx % Ncols;
    Wt[(size_t)n * K + k] = f2bf(W[idx]);
}

// ---------------- bf16 MFMA GEMM + fused attention scores ----------------
// 128x128 tile, BK=32. grid = (Nc/128, ceil(M/128)): col-tile fastest-varying so the
// 4 head-blocks of one row band dispatch adjacently -> A band fetched ~once (L2/LLC reuse).
// Epilogue also computes s,d partial dots for this block's head (col-tile == head):
// two wn-waves store disjoint halves s2[row][wn][h], summed later in edge_weights.

__global__ __launch_bounds__(256) void gemm_bf16(const unsigned short* __restrict__ A,
                                                 const unsigned short* __restrict__ Wt,
                                                 unsigned short* __restrict__ C,
                                                 const float* __restrict__ a_s,
                                                 const float* __restrict__ a_d,
                                                 float* __restrict__ s2, float* __restrict__ d2,
                                                 int M, int Nc, int K, int H) {
    __shared__ __align__(16) unsigned short As[128 * 32];
    __shared__ __align__(16) unsigned short Bs[128 * 32];
    const int tid = threadIdx.x;
    const int lane = tid & 63;
    const int wave = tid >> 6;
    const int wm = wave >> 1, wn = wave & 1;
    const int by = blockIdx.x;                 // col tile == head (Nc=512) or 0 (Nc=128)
    const int row0 = blockIdx.y * 128, col0 = by * 128;

    f32x4 acc[4][4];
    #pragma unroll
    for (int i = 0; i < 4; i++)
        #pragma unroll
        for (int j = 0; j < 4; j++)
            acc[i][j] = (f32x4){0.f, 0.f, 0.f, 0.f};

    const int ldm = tid >> 2;
    const int kpart = (tid & 3) * 8;
    const int khalf = (lane >> 4) * 8;
    const int fr = lane & 15;
    const int quad = lane >> 4;

    for (int k0 = 0; k0 < K; k0 += 32) {
        __syncthreads();
        #pragma unroll
        for (int i = 0; i < 2; i++) {
            int gr = row0 + i * 64 + ldm; if (gr >= M) gr = M - 1;
            gload_lds16(A + (size_t)gr * K + k0 + kpart, &As[i * 2048 + tid * 8]);
            int n = col0 + i * 64 + ldm;
            gload_lds16(Wt + (size_t)n * K + k0 + kpart, &Bs[i * 2048 + tid * 8]);
        }
        __syncthreads();
        short8 a[4], b[4];
        #pragma unroll
        for (int t = 0; t < 4; t++) {
            a[t] = *(const short8*)&As[(wm * 64 + t * 16 + fr) * 32 + khalf];
            b[t] = *(const short8*)&Bs[(wn * 64 + t * 16 + fr) * 32 + khalf];
        }
        #pragma unroll
        for (int mi = 0; mi < 4; mi++)
            #pragma unroll
            for (int ni = 0; ni < 4; ni++)
                acc[mi][ni] = __builtin_amdgcn_mfma_f32_16x16x32_bf16(
                    a[mi], b[ni], acc[mi][ni], 0, 0, 0);
    }

    // C store. C/D layout: col = lane&15, row = quad*4 + reg
    const int rbase = row0 + wm * 64 + quad * 4;
    const int cbase = col0 + wn * 64 + fr;
    #pragma unroll
    for (int mi = 0; mi < 4; mi++) {
        #pragma unroll
        for (int reg = 0; reg < 4; reg++) {
            int r = rbase + mi * 16 + reg;
            if (r < M) {
                #pragma unroll
                for (int ni = 0; ni < 4; ni++)
                    C[(size_t)r * Nc + cbase + ni * 16] = f2bf(acc[mi][ni][reg]);
            }
        }
    }

    // fused scores: channel (within head) for this lane = wn*64 + ni*16 + fr
    float asv[4], adv[4];
    #pragma unroll
    for (int ni = 0; ni < 4; ni++) {
        int c = by * 128 + wn * 64 + ni * 16 + fr;
        asv[ni] = a_s[c];
        adv[ni] = a_d[c];
    }
    float ps[4][4], pd[4][4];
    #pragma unroll
    for (int mi = 0; mi < 4; mi++)
        #pragma unroll
        for (int reg = 0; reg < 4; reg++) {
            float t = 0.f, u = 0.f;
            #pragma unroll
            for (int ni = 0; ni < 4; ni++) {
                t += acc[mi][ni][reg] * asv[ni];
                u += acc[mi][ni][reg] * adv[ni];
            }
            ps[mi][reg] = t;
            pd[mi][reg] = u;
        }
    // reduce over the 16 col-lanes (fr); offsets <16 stay within the quad group
    #pragma unroll
    for (int off = 1; off <= 8; off <<= 1)
        #pragma unroll
        for (int mi = 0; mi < 4; mi++)
            #pragma unroll
            for (int reg = 0; reg < 4; reg++) {
                ps[mi][reg] += __shfl_xor(ps[mi][reg], off, 64);
                pd[mi][reg] += __shfl_xor(pd[mi][reg], off, 64);
            }
    // lane fr writes row (mi=fr>>2, reg=fr&3)
    float oS = 0.f, oD = 0.f;
    #pragma unroll
    for (int mi = 0; mi < 4; mi++)
        #pragma unroll
        for (int reg = 0; reg < 4; reg++)
            if (fr == mi * 4 + reg) { oS = ps[mi][reg]; oD = pd[mi][reg]; }
    int rw = rbase + (fr >> 2) * 16 + (fr & 3);
    if (rw < M) {
        s2[(size_t)rw * (2 * H) + wn * H + by] = oS;
        d2[(size_t)rw * (2 * H) + wn * H + by] = oD;
    }
}

// ---------------- edge weights: wgt[pos][h] = exp(leaky(s[col]+d[dst])) ----------------
// s2/d2 hold two partial halves per (node,head): sum them here.

template <int H>
__global__ void edge_weights(const int* __restrict__ col, const int* __restrict__ dstn,
                             const float* __restrict__ s2, const float* __restrict__ d2,
                             float* __restrict__ wgt, int P) {
    int p = blockIdx.x * blockDim.x + threadIdx.x;
    if (p >= P) return;
    int sn = col[p], dn = dstn[p];
    if (H == 4) {
        float4 sa = *(const float4*)&s2[sn * 8];
        float4 sb = *(const float4*)&s2[sn * 8 + 4];
        float4 da = *(const float4*)&d2[dn * 8];
        float4 db = *(const float4*)&d2[dn * 8 + 4];
        float4 o;
        float e;
        e = sa.x + sb.x + da.x + db.x; e = e > 0.f ? e : NEG_SLOPE * e; o.x = __expf(e);
        e = sa.y + sb.y + da.y + db.y; e = e > 0.f ? e : NEG_SLOPE * e; o.y = __expf(e);
        e = sa.z + sb.z + da.z + db.z; e = e > 0.f ? e : NEG_SLOPE * e; o.z = __expf(e);
        e = sa.w + sb.w + da.w + db.w; e = e > 0.f ? e : NEG_SLOPE * e; o.w = __expf(e);
        *(float4*)&wgt[p * 4] = o;
    } else {
        float e = s2[sn * 2] + s2[sn * 2 + 1] + d2[dn * 2] + d2[dn * 2 + 1];
        e = e > 0.f ? e : NEG_SLOPE * e;
        wgt[p] = __expf(e);
    }
}

// ---------------- H=4 aggregation: one wave per node, full 1KB row/edge, unroll 8 ----------------

__global__ void gat_agg_h4(const unsigned short* __restrict__ h, const float* __restrict__ wgt,
                           const int* __restrict__ row_start, const int* __restrict__ col,
                           const float* __restrict__ bias,
                           const float* __restrict__ gam, const float* __restrict__ beta,
                           const float* __restrict__ rm, const float* __restrict__ rv,
                           unsigned short* __restrict__ out, int N) {
    int lane = threadIdx.x & 63;
    int wv = threadIdx.x >> 6;
    int n = blockIdx.x * 4 + wv;
    if (n >= N) return;
    int beg = row_start[n], end = row_start[n + 1];
    int hh = lane >> 4;
    int ch0 = lane * 8;

    float acc[8] = {0.f, 0.f, 0.f, 0.f, 0.f, 0.f, 0.f, 0.f};
    float denom = 0.f;

    for (int i = beg; i < end; i += 8) {
        uint4 raw[8]; float w[8];
        #pragma unroll
        for (int u = 0; u < 8; u++) {
            int e0 = i + u;
            int e = e0 < end ? e0 : end - 1;     // wave-uniform clamp; dup loads hit L1
            int sn = col[e];
            w[u] = (e0 < end) ? wgt[e * 4 + hh] : 0.f;
            raw[u] = *(const uint4*)&h[(size_t)sn * 512 + ch0];
        }
        #pragma unroll
        for (int u = 0; u < 8; u++) {
            denom += w[u];
            acc[0] += w[u] * bf2f((unsigned short)(raw[u].x & 0xffff));
            acc[1] += w[u] * bf2f((unsigned short)(raw[u].x >> 16));
            acc[2] += w[u] * bf2f((unsigned short)(raw[u].y & 0xffff));
            acc[3] += w[u] * bf2f((unsigned short)(raw[u].y >> 16));
            acc[4] += w[u] * bf2f((unsigned short)(raw[u].z & 0xffff));
            acc[5] += w[u] * bf2f((unsigned short)(raw[u].z >> 16));
            acc[6] += w[u] * bf2f((unsigned short)(raw[u].w & 0xffff));
            acc[7] += w[u] * bf2f((unsigned short)(raw[u].w >> 16));
        }
    }
    float inv = 1.f / denom;
    float v[8];
    #pragma unroll
    for (int c = 0; c < 8; c++) {
        int ch = ch0 + c;
        float t = acc[c] * inv + bias[ch];
        t = (t - rm[ch]) * (gam[ch] * rsqrtf(rv[ch] + BN_EPS)) + beta[ch];
        v[c] = t > 0.f ? t : expf(t) - 1.f;
    }
    uint4 p;
    p.x = (unsigned int)f2bf(v[0]) | ((unsigned int)f2bf(v[1]) << 16);
    p.y = (unsigned int)f2bf(v[2]) | ((unsigned int)f2bf(v[3]) << 16);
    p.z = (unsigned int)f2bf(v[4]) | ((unsigned int)f2bf(v[5]) << 16);
    p.w = (unsigned int)f2bf(v[6]) | ((unsigned int)f2bf(v[7]) << 16);
    *(uint4*)&out[(size_t)n * 512 + ch0] = p;
}

// ---------------- H=1 aggregation + BN + ELU + fused classifier -> d_out[N,2] ----------------

__global__ void gat_agg_h1_cls(const unsigned short* __restrict__ h, const float* __restrict__ wgt,
                               const int* __restrict__ row_start, const int* __restrict__ col,
                               const float* __restrict__ bias,
                               const float* __restrict__ gam, const float* __restrict__ beta,
                               const float* __restrict__ rm, const float* __restrict__ rv,
                               const float* __restrict__ Wc, const float* __restrict__ bc,
                               float* __restrict__ out, int N) {
    int lane = threadIdx.x & 63;
    int wv = threadIdx.x >> 6;
    int n = blockIdx.x * 4 + wv;
    if (n >= N) return;
    int beg = row_start[n], end = row_start[n + 1];
    int q = lane >> 4;
    int fl = lane & 15;
    const size_t hoff = fl * 8;

    float acc[8] = {0.f, 0.f, 0.f, 0.f, 0.f, 0.f, 0.f, 0.f};
    float denom = 0.f;

    for (int i = beg; i < end; i += 16) {
        uint4 raw[4]; float w[4];
        #pragma unroll
        for (int u = 0; u < 4; u++) {
            int e0 = i + u * 4 + q;
            int e = e0 < end ? e0 : end - 1;
            int sn = col[e];
            w[u] = (e0 < end) ? wgt[e] : 0.f;
            raw[u] = *(const uint4*)&h[(size_t)sn * 128 + hoff];
        }
        #pragma unroll
        for (int u = 0; u < 4; u++) {
            denom += w[u];
            acc[0] += w[u] * bf2f((unsigned short)(raw[u].x & 0xffff));
            acc[1] += w[u] * bf2f((unsigned short)(raw[u].x >> 16));
            acc[2] += w[u] * bf2f((unsigned short)(raw[u].y & 0xffff));
            acc[3] += w[u] * bf2f((unsigned short)(raw[u].y >> 16));
            acc[4] += w[u] * bf2f((unsigned short)(raw[u].z & 0xffff));
            acc[5] += w[u] * bf2f((unsigned short)(raw[u].z >> 16));
            acc[6] += w[u] * bf2f((unsigned short)(raw[u].w & 0xffff));
            acc[7] += w[u] * bf2f((unsigned short)(raw[u].w >> 16));
        }
    }
    #pragma unroll
    for (int c = 0; c < 8; c++) {
        acc[c] += __shfl_xor(acc[c], 16, 64);
        acc[c] += __shfl_xor(acc[c], 32, 64);
    }
    denom += __shfl_xor(denom, 16, 64);
    denom += __shfl_xor(denom, 32, 64);

    if (q == 0) {
        float inv = 1.f / denom;
        int ch0 = fl * 8;
        float p0 = 0.f, p1 = 0.f;
        #pragma unroll
        for (int c = 0; c < 8; c++) {
            int ch = ch0 + c;
            float t = acc[c] * inv + bias[ch];
            t = (t - rm[ch]) * (gam[ch] * rsqrtf(rv[ch] + BN_EPS)) + beta[ch];
            t = t > 0.f ? t : expf(t) - 1.f;
            p0 += t * Wc[ch * 2 + 0];
            p1 += t * Wc[ch * 2 + 1];
        }
        // reduce over the 16 active lanes (fl 0..15); partners stay within q==0
        #pragma unroll
        for (int off = 8; off >= 1; off >>= 1) {
            p0 += __shfl_xor(p0, off, 64);
            p1 += __shfl_xor(p1, off, 64);
        }
        if (fl == 0) {
            out[n * 2 + 0] = p0 + bc[0];
            out[n * 2 + 1] = p1 + bc[1];
        }
    }
}

// ---------------- launch ----------------

extern "C" void kernel_launch(void* const* d_in, const int* in_sizes, int n_in,
                              void* d_out, int out_size, void* d_ws, size_t ws_size,
                              hipStream_t stream) {
    const float* x   = (const float*)d_in[0];
    const int*   ei  = (const int*)d_in[1];
    const float* W1  = (const float*)d_in[2];
    const float* a1s = (const float*)d_in[3];
    const float* a1d = (const float*)d_in[4];
    const float* b1  = (const float*)d_in[5];
    const float* gm1 = (const float*)d_in[6];
    const float* be1 = (const float*)d_in[7];
    const float* rm1 = (const float*)d_in[8];
    const float* rv1 = (const float*)d_in[9];
    const float* W2  = (const float*)d_in[10];
    const float* a2s = (const float*)d_in[11];
    const float* a2d = (const float*)d_in[12];
    const float* b2  = (const float*)d_in[13];
    const float* gm2 = (const float*)d_in[14];
    const float* be2 = (const float*)d_in[15];
    const float* rm2 = (const float*)d_in[16];
    const float* rv2 = (const float*)d_in[17];
    const float* W3  = (const float*)d_in[18];
    const float* a3s = (const float*)d_in[19];
    const float* a3d = (const float*)d_in[20];
    const float* b3  = (const float*)d_in[21];
    const float* gm3 = (const float*)d_in[22];
    const float* be3 = (const float*)d_in[23];
    const float* rm3 = (const float*)d_in[24];
    const float* rv3 = (const float*)d_in[25];
    const float* Wc  = (const float*)d_in[26];
    const float* bc  = (const float*)d_in[27];

    int N = in_sizes[0] / IN_F;       // 50000
    int E = in_sizes[1] / 2;          // 400000
    int P = E + N;                    // CSR slots
    const int* srcA = ei;
    const int* dstA = ei + E;

    unsigned short* xb   = (unsigned short*)d_ws;        // N*768 bf16
    unsigned short* hbuf = xb + (size_t)N * 768;         // N*512 bf16
    unsigned short* gbuf = hbuf + (size_t)N * 512;       // N*512 bf16
    float* s2   = (float*)(gbuf + (size_t)N * 512);      // N*8 (two halves x 4 heads)
    float* d2   = s2 + (size_t)N * 8;                    // N*8
    float* wgt  = d2 + (size_t)N * 8;                    // P*4
    unsigned short* Wt1 = (unsigned short*)(wgt + (size_t)P * 4);  // 512*768
    unsigned short* Wt2 = Wt1 + 512 * 768;               // 512*512
    unsigned short* Wt3 = Wt2 + 512 * 512;               // 128*512
    int* count     = (int*)(Wt3 + 128 * 512);
    int* cursor    = count + N;
    int* row_start = cursor + N;
    int* col       = row_start + N + 1;                  // P
    int* dstn      = col + P;                            // P

    // CSR (rebuild every call: ws re-poisoned)
    init_counts<<<(N + 255) / 256, 256, 0, stream>>>(count, cursor, N);
    count_edges<<<(E + 255) / 256, 256, 0, stream>>>(dstA, E, count);
    scan_counts<<<1, 1024, 0, stream>>>(count, row_start, N);
    scatter_edges<<<(E + N + 255) / 256, 256, 0, stream>>>(srcA, dstA, E, N, row_start,
                                                           cursor, col, dstn);
    // casts
    long xtot = (long)N * IN_F;
    cast_x_bf16<<<(int)((xtot / 4 + 255) / 256), 256, 0, stream>>>(x, xb, xtot);
    cast_transpose_w<<<(768 * 512 + 255) / 256, 256, 0, stream>>>(W1, Wt1, 768, 512);
    cast_transpose_w<<<(512 * 512 + 255) / 256, 256, 0, stream>>>(W2, Wt2, 512, 512);
    cast_transpose_w<<<(512 * 128 + 255) / 256, 256, 0, stream>>>(W3, Wt3, 512, 128);

    int Mb = (N + 127) / 128;
    int Nb4 = (N + 3) / 4;

    // Layer 1
    gemm_bf16<<<dim3(4, Mb), 256, 0, stream>>>(xb, Wt1, hbuf, a1s, a1d, s2, d2, N, 512, 768, 4);
    edge_weights<4><<<(P + 255) / 256, 256, 0, stream>>>(col, dstn, s2, d2, wgt, P);
    gat_agg_h4<<<Nb4, 256, 0, stream>>>(hbuf, wgt, row_start, col,
                                        b1, gm1, be1, rm1, rv1, gbuf, N);
    // Layer 2
    gemm_bf16<<<dim3(4, Mb), 256, 0, stream>>>(gbuf, Wt2, hbuf, a2s, a2d, s2, d2, N, 512, 512, 4);
    edge_weights<4><<<(P + 255) / 256, 256, 0, stream>>>(col, dstn, s2, d2, wgt, P);
    gat_agg_h4<<<Nb4, 256, 0, stream>>>(hbuf, wgt, row_start, col,
                                        b2, gm2, be2, rm2, rv2, gbuf, N);
    // Layer 3 (1 head) + fused classifier
    gemm_bf16<<<dim3(1, Mb), 256, 0, stream>>>(gbuf, Wt3, hbuf, a3s, a3d, s2, d2, N, 128, 512, 1);
    edge_weights<1><<<(P + 255) / 256, 256, 0, stream>>>(col, dstn, s2, d2, wgt, P);
    gat_agg_h1_cls<<<Nb4, 256, 0, stream>>>(hbuf, wgt, row_start, col,
                                            b3, gm3, be3, rm3, rv3, Wc, bc, (float*)d_out, N);
}

// Round 7
// 690.879 us; speedup vs baseline: 2.9114x; 1.0613x over previous
//
#include <hip/hip_runtime.h>
#include <hip/hip_bf16.h>
#include <math.h>

constexpr int IN_F = 768;
constexpr float NEG_SLOPE = 0.2f;
constexpr float BN_EPS = 1e-5f;

typedef __attribute__((ext_vector_type(8))) short short8;
typedef __attribute__((ext_vector_type(4))) float f32x4;

__device__ inline float bf2f(unsigned short u) {
    unsigned int x = ((unsigned int)u) << 16;
    return __uint_as_float(x);
}
__device__ inline unsigned short f2bf(float f) {
    __hip_bfloat16 h = __float2bfloat16(f);
    return *(unsigned short*)&h;
}
__device__ inline void gload_lds16(const unsigned short* g, unsigned short* l) {
    __builtin_amdgcn_global_load_lds(
        (const __attribute__((address_space(1))) void*)g,
        (__attribute__((address_space(3))) void*)l, 16, 0, 0);
}

// ---------------- CSR build ----------------

__global__ void init_counts(int* __restrict__ count, int* __restrict__ cursor, int N) {
    int i = blockIdx.x * blockDim.x + threadIdx.x;
    if (i < N) { count[i] = 1; cursor[i] = 0; }  // self-loop included
}

__global__ void count_edges(const int* __restrict__ dst, int E, int* __restrict__ count) {
    int e = blockIdx.x * blockDim.x + threadIdx.x;
    if (e < E) atomicAdd(&count[dst[e]], 1);
}

__global__ void scan_counts(const int* __restrict__ count, int* __restrict__ row_start, int N) {
    __shared__ int wsum[17];
    __shared__ int carry;
    int tid = threadIdx.x;
    int lane = tid & 63, w = tid >> 6;
    if (tid == 0) carry = 0;
    __syncthreads();
    for (int base = 0; base < N; base += 4096) {
        int idx = base + tid * 4;
        int v0 = (idx + 0 < N) ? count[idx + 0] : 0;
        int v1 = (idx + 1 < N) ? count[idx + 1] : 0;
        int v2 = (idx + 2 < N) ? count[idx + 2] : 0;
        int v3 = (idx + 3 < N) ? count[idx + 3] : 0;
        int tsum = v0 + v1 + v2 + v3;
        int x = tsum;
        #pragma unroll
        for (int off = 1; off < 64; off <<= 1) {
            int y = __shfl_up(x, off, 64);
            if (lane >= off) x += y;
        }
        if (lane == 63) wsum[w] = x;
        __syncthreads();
        if (tid == 0) {
            int r = 0;
            for (int i = 0; i < 16; i++) { int t = wsum[i]; wsum[i] = r; r += t; }
            wsum[16] = r;
        }
        __syncthreads();
        int excl = carry + wsum[w] + (x - tsum);
        if (idx + 0 < N) row_start[idx + 0] = excl;
        if (idx + 1 < N) row_start[idx + 1] = excl + v0;
        if (idx + 2 < N) row_start[idx + 2] = excl + v0 + v1;
        if (idx + 3 < N) row_start[idx + 3] = excl + v0 + v1 + v2;
        __syncthreads();
        if (tid == 0) carry += wsum[16];
        __syncthreads();
    }
    if (tid == 0) row_start[N] = carry;
}

__global__ void scatter_edges(const int* __restrict__ srcA, const int* __restrict__ dstA,
                              int E, int N, const int* __restrict__ row_start,
                              int* __restrict__ cursor, int* __restrict__ col,
                              int* __restrict__ dstn) {
    int i = blockIdx.x * blockDim.x + threadIdx.x;
    if (i < E) {
        int d = dstA[i];
        int pos = row_start[d] + atomicAdd(&cursor[d], 1);
        col[pos] = srcA[i];
        dstn[pos] = d;
    } else if (i < E + N) {
        int n = i - E;
        int pos = row_start[n] + atomicAdd(&cursor[n], 1);
        col[pos] = n;
        dstn[pos] = n;
    }
}

// ---------------- casts ----------------

__global__ void cast_x_bf16(const float* __restrict__ x, unsigned short* __restrict__ xb,
                            long total) {
    long i = ((long)blockIdx.x * blockDim.x + threadIdx.x) * 4;
    if (i >= total) return;
    float4 v = *(const float4*)&x[i];
    *(ushort2*)&xb[i] = make_ushort2(f2bf(v.x), f2bf(v.y));
    *(ushort2*)&xb[i + 2] = make_ushort2(f2bf(v.z), f2bf(v.w));
}

// all three W [K][Ncols] fp32 -> Wt [Ncols][K] bf16, one launch
__global__ void cast_w_all(const float* __restrict__ W1, const float* __restrict__ W2,
                           const float* __restrict__ W3, unsigned short* __restrict__ Wt1,
                           unsigned short* __restrict__ Wt2, unsigned short* __restrict__ Wt3) {
    int idx = blockIdx.x * blockDim.x + threadIdx.x;
    const int S1 = 768 * 512, S2 = 512 * 512, S3 = 512 * 128;
    if (idx < S1) {
        int k = idx / 512, n = idx % 512;
        Wt1[(size_t)n * 768 + k] = f2bf(W1[idx]);
    } else if (idx < S1 + S2) {
        int j = idx - S1;
        int k = j / 512, n = j % 512;
        Wt2[(size_t)n * 512 + k] = f2bf(W2[j]);
    } else if (idx < S1 + S2 + S3) {
        int j = idx - S1 - S2;
        int k = j / 128, n = j % 128;
        Wt3[(size_t)n * 512 + k] = f2bf(W3[j]);
    }
}

// ---------------- bf16 MFMA GEMM + fused attention scores ----------------
// 128x128 tile, BK=32. 1D grid with XCD-aware mapping: l = (g*HT + h)*8 + x puts all
// head-tiles of row bands g*8+x on XCD x consecutively -> each A band L2-fetched once.
// LDS k-chunk XOR swizzle kills the 4-way ds_read_b128 bank conflict.
// Epilogue computes s,d partial dots; two wn-waves store halves s2[row][wn][h].

__global__ __launch_bounds__(256, 3) void gemm_bf16(const unsigned short* __restrict__ A,
                                                    const unsigned short* __restrict__ Wt,
                                                    unsigned short* __restrict__ C,
                                                    const float* __restrict__ a_s,
                                                    const float* __restrict__ a_d,
                                                    float* __restrict__ s2,
                                                    float* __restrict__ d2,
                                                    int M, int Nc, int K, int H) {
    __shared__ __align__(16) unsigned short As[128 * 32];
    __shared__ __align__(16) unsigned short Bs[128 * 32];
    const int tid = threadIdx.x;
    const int lane = tid & 63;
    const int wave = tid >> 6;
    const int wm = wave >> 1, wn = wave & 1;

    // XCD-aware block mapping (8 XCDs, dispatch round-robin ~ blockIdx%8)
    const int l = blockIdx.x;
    const int x = l & 7;
    const int t0 = l >> 3;
    const int HT = Nc >> 7;                       // head tiles: 4 or 1
    const int by = (HT == 4) ? (t0 & 3) : 0;      // head
    const int g  = (HT == 4) ? (t0 >> 2) : t0;
    const int rb = g * 8 + x;                     // row band
    const int row0 = rb * 128, col0 = by * 128;
    if (row0 >= M) return;

    f32x4 acc[4][4];
    #pragma unroll
    for (int i = 0; i < 4; i++)
        #pragma unroll
        for (int j = 0; j < 4; j++)
            acc[i][j] = (f32x4){0.f, 0.f, 0.f, 0.f};

    const int ldm = tid >> 2;
    // staging k-chunk swizzle: LDS chunk (tid&3) of row (tid>>2) holds data chunk (tid&3)^(row&3)
    const int kpart = (((tid & 3) ^ ((tid >> 2) & 3)) * 8);
    const int fr = lane & 15;
    const int quad = lane >> 4;
    const int kchunk8 = ((quad ^ (fr & 3)) * 8);  // read-side swizzled chunk offset (shorts)

    for (int k0 = 0; k0 < K; k0 += 32) {
        __syncthreads();
        #pragma unroll
        for (int i = 0; i < 2; i++) {
            int gr = row0 + i * 64 + ldm; if (gr >= M) gr = M - 1;
            gload_lds16(A + (size_t)gr * K + k0 + kpart, &As[i * 2048 + tid * 8]);
            int n = col0 + i * 64 + ldm;
            gload_lds16(Wt + (size_t)n * K + k0 + kpart, &Bs[i * 2048 + tid * 8]);
        }
        __syncthreads();
        short8 a[4], b[4];
        #pragma unroll
        for (int tt = 0; tt < 4; tt++) {
            a[tt] = *(const short8*)&As[(wm * 64 + tt * 16 + fr) * 32 + kchunk8];
            b[tt] = *(const short8*)&Bs[(wn * 64 + tt * 16 + fr) * 32 + kchunk8];
        }
        #pragma unroll
        for (int mi = 0; mi < 4; mi++)
            #pragma unroll
            for (int ni = 0; ni < 4; ni++)
                acc[mi][ni] = __builtin_amdgcn_mfma_f32_16x16x32_bf16(
                    a[mi], b[ni], acc[mi][ni], 0, 0, 0);
    }

    // C store. C/D layout: col = lane&15, row = quad*4 + reg
    const int rbase = row0 + wm * 64 + quad * 4;
    const int cbase = col0 + wn * 64 + fr;
    #pragma unroll
    for (int mi = 0; mi < 4; mi++) {
        #pragma unroll
        for (int reg = 0; reg < 4; reg++) {
            int r = rbase + mi * 16 + reg;
            if (r < M) {
                #pragma unroll
                for (int ni = 0; ni < 4; ni++)
                    C[(size_t)r * Nc + cbase + ni * 16] = f2bf(acc[mi][ni][reg]);
            }
        }
    }

    // fused scores: channel (within head) for this lane = wn*64 + ni*16 + fr
    float asv[4], adv[4];
    #pragma unroll
    for (int ni = 0; ni < 4; ni++) {
        int c = by * 128 + wn * 64 + ni * 16 + fr;
        asv[ni] = a_s[c];
        adv[ni] = a_d[c];
    }
    float ps[4][4], pd[4][4];
    #pragma unroll
    for (int mi = 0; mi < 4; mi++)
        #pragma unroll
        for (int reg = 0; reg < 4; reg++) {
            float t = 0.f, u = 0.f;
            #pragma unroll
            for (int ni = 0; ni < 4; ni++) {
                t += acc[mi][ni][reg] * asv[ni];
                u += acc[mi][ni][reg] * adv[ni];
            }
            ps[mi][reg] = t;
            pd[mi][reg] = u;
        }
    #pragma unroll
    for (int off = 1; off <= 8; off <<= 1)
        #pragma unroll
        for (int mi = 0; mi < 4; mi++)
            #pragma unroll
            for (int reg = 0; reg < 4; reg++) {
                ps[mi][reg] += __shfl_xor(ps[mi][reg], off, 64);
                pd[mi][reg] += __shfl_xor(pd[mi][reg], off, 64);
            }
    float oS = 0.f, oD = 0.f;
    #pragma unroll
    for (int mi = 0; mi < 4; mi++)
        #pragma unroll
        for (int reg = 0; reg < 4; reg++)
            if (fr == mi * 4 + reg) { oS = ps[mi][reg]; oD = pd[mi][reg]; }
    int rw = rbase + (fr >> 2) * 16 + (fr & 3);
    if (rw < M) {
        s2[(size_t)rw * (2 * H) + wn * H + by] = oS;
        d2[(size_t)rw * (2 * H) + wn * H + by] = oD;
    }
}

// ---------------- edge weights: wgt[pos][h] = exp(leaky(s[col]+d[dst])) ----------------

template <int H>
__global__ void edge_weights(const int* __restrict__ col, const int* __restrict__ dstn,
                             const float* __restrict__ s2, const float* __restrict__ d2,
                             float* __restrict__ wgt, int P) {
    int p = blockIdx.x * blockDim.x + threadIdx.x;
    if (p >= P) return;
    int sn = col[p], dn = dstn[p];
    if (H == 4) {
        float4 sa = *(const float4*)&s2[sn * 8];
        float4 sb = *(const float4*)&s2[sn * 8 + 4];
        float4 da = *(const float4*)&d2[dn * 8];
        float4 db = *(const float4*)&d2[dn * 8 + 4];
        float4 o;
        float e;
        e = sa.x + sb.x + da.x + db.x; e = e > 0.f ? e : NEG_SLOPE * e; o.x = __expf(e);
        e = sa.y + sb.y + da.y + db.y; e = e > 0.f ? e : NEG_SLOPE * e; o.y = __expf(e);
        e = sa.z + sb.z + da.z + db.z; e = e > 0.f ? e : NEG_SLOPE * e; o.z = __expf(e);
        e = sa.w + sb.w + da.w + db.w; e = e > 0.f ? e : NEG_SLOPE * e; o.w = __expf(e);
        *(float4*)&wgt[p * 4] = o;
    } else {
        float e = s2[sn * 2] + s2[sn * 2 + 1] + d2[dn * 2] + d2[dn * 2 + 1];
        e = e > 0.f ? e : NEG_SLOPE * e;
        wgt[p] = __expf(e);
    }
}

// ---------------- H=4 aggregation: one wave per node, full 1KB row/edge, unroll 8 ----------------

__global__ void gat_agg_h4(const unsigned short* __restrict__ h, const float* __restrict__ wgt,
                           const int* __restrict__ row_start, const int* __restrict__ col,
                           const float* __restrict__ bias,
                           const float* __restrict__ gam, const float* __restrict__ beta,
                           const float* __restrict__ rm, const float* __restrict__ rv,
                           unsigned short* __restrict__ out, int N) {
    int lane = threadIdx.x & 63;
    int wv = threadIdx.x >> 6;
    int n = blockIdx.x * 4 + wv;
    if (n >= N) return;
    int beg = row_start[n], end = row_start[n + 1];
    int hh = lane >> 4;
    int ch0 = lane * 8;

    float acc[8] = {0.f, 0.f, 0.f, 0.f, 0.f, 0.f, 0.f, 0.f};
    float denom = 0.f;

    for (int i = beg; i < end; i += 8) {
        uint4 raw[8]; float w[8];
        #pragma unroll
        for (int u = 0; u < 8; u++) {
            int e0 = i + u;
            int e = e0 < end ? e0 : end - 1;     // wave-uniform clamp; dup loads hit L1
            int sn = col[e];
            w[u] = (e0 < end) ? wgt[e * 4 + hh] : 0.f;
            raw[u] = *(const uint4*)&h[(size_t)sn * 512 + ch0];
        }
        #pragma unroll
        for (int u = 0; u < 8; u++) {
            denom += w[u];
            acc[0] += w[u] * bf2f((unsigned short)(raw[u].x & 0xffff));
            acc[1] += w[u] * bf2f((unsigned short)(raw[u].x >> 16));
            acc[2] += w[u] * bf2f((unsigned short)(raw[u].y & 0xffff));
            acc[3] += w[u] * bf2f((unsigned short)(raw[u].y >> 16));
            acc[4] += w[u] * bf2f((unsigned short)(raw[u].z & 0xffff));
            acc[5] += w[u] * bf2f((unsigned short)(raw[u].z >> 16));
            acc[6] += w[u] * bf2f((unsigned short)(raw[u].w & 0xffff));
            acc[7] += w[u] * bf2f((unsigned short)(raw[u].w >> 16));
        }
    }
    float inv = 1.f / denom;
    float v[8];
    #pragma unroll
    for (int c = 0; c < 8; c++) {
        int ch = ch0 + c;
        float t = acc[c] * inv + bias[ch];
        t = (t - rm[ch]) * (gam[ch] * rsqrtf(rv[ch] + BN_EPS)) + beta[ch];
        v[c] = t > 0.f ? t : expf(t) - 1.f;
    }
    uint4 p;
    p.x = (unsigned int)f2bf(v[0]) | ((unsigned int)f2bf(v[1]) << 16);
    p.y = (unsigned int)f2bf(v[2]) | ((unsigned int)f2bf(v[3]) << 16);
    p.z = (unsigned int)f2bf(v[4]) | ((unsigned int)f2bf(v[5]) << 16);
    p.w = (unsigned int)f2bf(v[6]) | ((unsigned int)f2bf(v[7]) << 16);
    *(uint4*)&out[(size_t)n * 512 + ch0] = p;
}

// ---------------- H=1 aggregation + BN + ELU + fused classifier -> d_out[N,2] ----------------

__global__ void gat_agg_h1_cls(const unsigned short* __restrict__ h, const float* __restrict__ wgt,
                               const int* __restrict__ row_start, const int* __restrict__ col,
                               const float* __restrict__ bias,
                               const float* __restrict__ gam, const float* __restrict__ beta,
                               const float* __restrict__ rm, const float* __restrict__ rv,
                               const float* __restrict__ Wc, const float* __restrict__ bc,
                               float* __restrict__ out, int N) {
    int lane = threadIdx.x & 63;
    int wv = threadIdx.x >> 6;
    int n = blockIdx.x * 4 + wv;
    if (n >= N) return;
    int beg = row_start[n], end = row_start[n + 1];
    int q = lane >> 4;
    int fl = lane & 15;
    const size_t hoff = fl * 8;

    float acc[8] = {0.f, 0.f, 0.f, 0.f, 0.f, 0.f, 0.f, 0.f};
    float denom = 0.f;

    for (int i = beg; i < end; i += 16) {
        uint4 raw[4]; float w[4];
        #pragma unroll
        for (int u = 0; u < 4; u++) {
            int e0 = i + u * 4 + q;
            int e = e0 < end ? e0 : end - 1;
            int sn = col[e];
            w[u] = (e0 < end) ? wgt[e] : 0.f;
            raw[u] = *(const uint4*)&h[(size_t)sn * 128 + hoff];
        }
        #pragma unroll
        for (int u = 0; u < 4; u++) {
            denom += w[u];
            acc[0] += w[u] * bf2f((unsigned short)(raw[u].x & 0xffff));
            acc[1] += w[u] * bf2f((unsigned short)(raw[u].x >> 16));
            acc[2] += w[u] * bf2f((unsigned short)(raw[u].y & 0xffff));
            acc[3] += w[u] * bf2f((unsigned short)(raw[u].y >> 16));
            acc[4] += w[u] * bf2f((unsigned short)(raw[u].z & 0xffff));
            acc[5] += w[u] * bf2f((unsigned short)(raw[u].z >> 16));
            acc[6] += w[u] * bf2f((unsigned short)(raw[u].w & 0xffff));
            acc[7] += w[u] * bf2f((unsigned short)(raw[u].w >> 16));
        }
    }
    #pragma unroll
    for (int c = 0; c < 8; c++) {
        acc[c] += __shfl_xor(acc[c], 16, 64);
        acc[c] += __shfl_xor(acc[c], 32, 64);
    }
    denom += __shfl_xor(denom, 16, 64);
    denom += __shfl_xor(denom, 32, 64);

    if (q == 0) {
        float inv = 1.f / denom;
        int ch0 = fl * 8;
        float p0 = 0.f, p1 = 0.f;
        #pragma unroll
        for (int c = 0; c < 8; c++) {
            int ch = ch0 + c;
            float t = acc[c] * inv + bias[ch];
            t = (t - rm[ch]) * (gam[ch] * rsqrtf(rv[ch] + BN_EPS)) + beta[ch];
            t = t > 0.f ? t : expf(t) - 1.f;
            p0 += t * Wc[ch * 2 + 0];
            p1 += t * Wc[ch * 2 + 1];
        }
        #pragma unroll
        for (int off = 8; off >= 1; off >>= 1) {
            p0 += __shfl_xor(p0, off, 64);
            p1 += __shfl_xor(p1, off, 64);
        }
        if (fl == 0) {
            out[n * 2 + 0] = p0 + bc[0];
            out[n * 2 + 1] = p1 + bc[1];
        }
    }
}

// ---------------- launch ----------------

extern "C" void kernel_launch(void* const* d_in, const int* in_sizes, int n_in,
                              void* d_out, int out_size, void* d_ws, size_t ws_size,
                              hipStream_t stream) {
    const float* x   = (const float*)d_in[0];
    const int*   ei  = (const int*)d_in[1];
    const float* W1  = (const float*)d_in[2];
    const float* a1s = (const float*)d_in[3];
    const float* a1d = (const float*)d_in[4];
    const float* b1  = (const float*)d_in[5];
    const float* gm1 = (const float*)d_in[6];
    const float* be1 = (const float*)d_in[7];
    const float* rm1 = (const float*)d_in[8];
    const float* rv1 = (const float*)d_in[9];
    const float* W2  = (const float*)d_in[10];
    const float* a2s = (const float*)d_in[11];
    const float* a2d = (const float*)d_in[12];
    const float* b2  = (const float*)d_in[13];
    const float* gm2 = (const float*)d_in[14];
    const float* be2 = (const float*)d_in[15];
    const float* rm2 = (const float*)d_in[16];
    const float* rv2 = (const float*)d_in[17];
    const float* W3  = (const float*)d_in[18];
    const float* a3s = (const float*)d_in[19];
    const float* a3d = (const float*)d_in[20];
    const float* b3  = (const float*)d_in[21];
    const float* gm3 = (const float*)d_in[22];
    const float* be3 = (const float*)d_in[23];
    const float* rm3 = (const float*)d_in[24];
    const float* rv3 = (const float*)d_in[25];
    const float* Wc  = (const float*)d_in[26];
    const float* bc  = (const float*)d_in[27];

    int N = in_sizes[0] / IN_F;       // 50000
    int E = in_sizes[1] / 2;          // 400000
    int P = E + N;                    // CSR slots
    const int* srcA = ei;
    const int* dstA = ei + E;

    unsigned short* xb   = (unsigned short*)d_ws;        // N*768 bf16
    unsigned short* hbuf = xb + (size_t)N * 768;         // N*512 bf16
    unsigned short* gbuf = hbuf + (size_t)N * 512;       // N*512 bf16
    float* s2   = (float*)(gbuf + (size_t)N * 512);      // N*8 (two halves x 4 heads)
    float* d2   = s2 + (size_t)N * 8;                    // N*8
    float* wgt  = d2 + (size_t)N * 8;                    // P*4
    unsigned short* Wt1 = (unsigned short*)(wgt + (size_t)P * 4);  // 512*768
    unsigned short* Wt2 = Wt1 + 512 * 768;               // 512*512
    unsigned short* Wt3 = Wt2 + 512 * 512;               // 128*512
    int* count     = (int*)(Wt3 + 128 * 512);
    int* cursor    = count + N;
    int* row_start = cursor + N;
    int* col       = row_start + N + 1;                  // P
    int* dstn      = col + P;                            // P

    // CSR (rebuild every call: ws re-poisoned)
    init_counts<<<(N + 255) / 256, 256, 0, stream>>>(count, cursor, N);
    count_edges<<<(E + 255) / 256, 256, 0, stream>>>(dstA, E, count);
    scan_counts<<<1, 1024, 0, stream>>>(count, row_start, N);
    scatter_edges<<<(E + N + 255) / 256, 256, 0, stream>>>(srcA, dstA, E, N, row_start,
                                                           cursor, col, dstn);
    // casts
    long xtot = (long)N * IN_F;
    cast_x_bf16<<<(int)((xtot / 4 + 255) / 256), 256, 0, stream>>>(x, xb, xtot);
    cast_w_all<<<(768 * 512 + 512 * 512 + 512 * 128 + 255) / 256, 256, 0, stream>>>(
        W1, W2, W3, Wt1, Wt2, Wt3);

    int Mb = (N + 127) / 128;          // 391
    int MbP = (Mb + 7) & ~7;           // 392, multiple of 8 for XCD mapping
    int Nb4 = (N + 3) / 4;

    // Layer 1
    gemm_bf16<<<4 * MbP, 256, 0, stream>>>(xb, Wt1, hbuf, a1s, a1d, s2, d2, N, 512, 768, 4);
    edge_weights<4><<<(P + 255) / 256, 256, 0, stream>>>(col, dstn, s2, d2, wgt, P);
    gat_agg_h4<<<Nb4, 256, 0, stream>>>(hbuf, wgt, row_start, col,
                                        b1, gm1, be1, rm1, rv1, gbuf, N);
    // Layer 2
    gemm_bf16<<<4 * MbP, 256, 0, stream>>>(gbuf, Wt2, hbuf, a2s, a2d, s2, d2, N, 512, 512, 4);
    edge_weights<4><<<(P + 255) / 256, 256, 0, stream>>>(col, dstn, s2, d2, wgt, P);
    gat_agg_h4<<<Nb4, 256, 0, stream>>>(hbuf, wgt, row_start, col,
                                        b2, gm2, be2, rm2, rv2, gbuf, N);
    // Layer 3 (1 head) + fused classifier
    gemm_bf16<<<MbP, 256, 0, stream>>>(gbuf, Wt3, hbuf, a3s, a3d, s2, d2, N, 128, 512, 1);
    edge_weights<1><<<(P + 255) / 256, 256, 0, stream>>>(col, dstn, s2, d2, wgt, P);
    gat_agg_h1_cls<<<Nb4, 256, 0, stream>>>(hbuf, wgt, row_start, col,
                                            b3, gm3, be3, rm3, rv3, Wc, bc, (float*)d_out, N);
}

// Round 8
// 650.461 us; speedup vs baseline: 3.0923x; 1.0621x over previous
//
#include <hip/hip_runtime.h>
#include <hip/hip_bf16.h>
#include <math.h>

constexpr int IN_F = 768;
constexpr float NEG_SLOPE = 0.2f;
constexpr float BN_EPS = 1e-5f;

typedef __attribute__((ext_vector_type(8))) short short8;
typedef __attribute__((ext_vector_type(4))) float f32x4;

__device__ inline float bf2f(unsigned short u) {
    unsigned int x = ((unsigned int)u) << 16;
    return __uint_as_float(x);
}
__device__ inline unsigned short f2bf(float f) {
    __hip_bfloat16 h = __float2bfloat16(f);
    return *(unsigned short*)&h;
}
__device__ inline void gload_lds16(const unsigned short* g, unsigned short* l) {
    __builtin_amdgcn_global_load_lds(
        (const __attribute__((address_space(1))) void*)g,
        (__attribute__((address_space(3))) void*)l, 16, 0, 0);
}

// ---------------- CSR build ----------------

__global__ void init_counts(int* __restrict__ count, int* __restrict__ cursor, int N) {
    int i = blockIdx.x * blockDim.x + threadIdx.x;
    if (i < N) { count[i] = 1; cursor[i] = 0; }  // self-loop included
}

__global__ void count_edges(const int* __restrict__ dst, int E, int* __restrict__ count) {
    int e = blockIdx.x * blockDim.x + threadIdx.x;
    if (e < E) atomicAdd(&count[dst[e]], 1);
}

__global__ void scan_counts(const int* __restrict__ count, int* __restrict__ row_start, int N) {
    __shared__ int wsum[17];
    __shared__ int carry;
    int tid = threadIdx.x;
    int lane = tid & 63, w = tid >> 6;
    if (tid == 0) carry = 0;
    __syncthreads();
    for (int base = 0; base < N; base += 4096) {
        int idx = base + tid * 4;
        int v0 = (idx + 0 < N) ? count[idx + 0] : 0;
        int v1 = (idx + 1 < N) ? count[idx + 1] : 0;
        int v2 = (idx + 2 < N) ? count[idx + 2] : 0;
        int v3 = (idx + 3 < N) ? count[idx + 3] : 0;
        int tsum = v0 + v1 + v2 + v3;
        int x = tsum;
        #pragma unroll
        for (int off = 1; off < 64; off <<= 1) {
            int y = __shfl_up(x, off, 64);
            if (lane >= off) x += y;
        }
        if (lane == 63) wsum[w] = x;
        __syncthreads();
        if (tid == 0) {
            int r = 0;
            for (int i = 0; i < 16; i++) { int t = wsum[i]; wsum[i] = r; r += t; }
            wsum[16] = r;
        }
        __syncthreads();
        int excl = carry + wsum[w] + (x - tsum);
        if (idx + 0 < N) row_start[idx + 0] = excl;
        if (idx + 1 < N) row_start[idx + 1] = excl + v0;
        if (idx + 2 < N) row_start[idx + 2] = excl + v0 + v1;
        if (idx + 3 < N) row_start[idx + 3] = excl + v0 + v1 + v2;
        __syncthreads();
        if (tid == 0) carry += wsum[16];
        __syncthreads();
    }
    if (tid == 0) row_start[N] = carry;
}

__global__ void scatter_edges(const int* __restrict__ srcA, const int* __restrict__ dstA,
                              int E, int N, const int* __restrict__ row_start,
                              int* __restrict__ cursor, int* __restrict__ col,
                              int* __restrict__ dstn) {
    int i = blockIdx.x * blockDim.x + threadIdx.x;
    if (i < E) {
        int d = dstA[i];
        int pos = row_start[d] + atomicAdd(&cursor[d], 1);
        col[pos] = srcA[i];
        dstn[pos] = d;
    } else if (i < E + N) {
        int n = i - E;
        int pos = row_start[n] + atomicAdd(&cursor[n], 1);
        col[pos] = n;
        dstn[pos] = n;
    }
}

// ---------------- casts: x -> bf16 and all three W -> Wt bf16, one launch ----------------

__global__ void cast_all(const float* __restrict__ x, unsigned short* __restrict__ xb, long xq,
                         const float* __restrict__ W1, const float* __restrict__ W2,
                         const float* __restrict__ W3, unsigned short* __restrict__ Wt1,
                         unsigned short* __restrict__ Wt2, unsigned short* __restrict__ Wt3) {
    long t = (long)blockIdx.x * blockDim.x + threadIdx.x;
    const int S1 = 768 * 512, S2 = 512 * 512, S3 = 512 * 128;
    if (t < xq) {
        long i = t * 4;
        float4 v = *(const float4*)&x[i];
        *(ushort2*)&xb[i] = make_ushort2(f2bf(v.x), f2bf(v.y));
        *(ushort2*)&xb[i + 2] = make_ushort2(f2bf(v.z), f2bf(v.w));
    } else {
        long j = t - xq;
        if (j < S1) {
            int k = (int)j / 512, n = (int)j % 512;
            Wt1[(size_t)n * 768 + k] = f2bf(W1[j]);
        } else if (j < S1 + S2) {
            int jj = (int)(j - S1);
            int k = jj / 512, n = jj % 512;
            Wt2[(size_t)n * 512 + k] = f2bf(W2[jj]);
        } else if (j < S1 + S2 + S3) {
            int jj = (int)(j - S1 - S2);
            int k = jj / 128, n = jj % 128;
            Wt3[(size_t)n * 512 + k] = f2bf(W3[jj]);
        }
    }
}

// ---------------- bf16 MFMA GEMM + fused attention scores ----------------
// 128x128 tile, BK=64 (half the barrier drains of BK=32). XCD-aware 1D grid mapping.
// 8-chunk XOR swizzle: physical slot c of row r holds data chunk c^(r&7) -> every
// consecutive-8-lane group of a ds_read_b128 covers 8 distinct bank-quads.
// Epilogue computes s,d partial dots; two wn-waves store halves s2[row][wn][h].

__global__ __launch_bounds__(256, 3) void gemm_bf16(const unsigned short* __restrict__ A,
                                                    const unsigned short* __restrict__ Wt,
                                                    unsigned short* __restrict__ C,
                                                    const float* __restrict__ a_s,
                                                    const float* __restrict__ a_d,
                                                    float* __restrict__ s2,
                                                    float* __restrict__ d2,
                                                    int M, int Nc, int K, int H) {
    __shared__ __align__(16) unsigned short As[128 * 64];
    __shared__ __align__(16) unsigned short Bs[128 * 64];
    const int tid = threadIdx.x;
    const int lane = tid & 63;
    const int wave = tid >> 6;
    const int wm = wave >> 1, wn = wave & 1;

    // XCD-aware block mapping (8 XCDs, dispatch round-robin ~ blockIdx%8)
    const int l = blockIdx.x;
    const int x = l & 7;
    const int t0 = l >> 3;
    const int HT = Nc >> 7;                       // head tiles: 4 or 1
    const int by = (HT == 4) ? (t0 & 3) : 0;      // head
    const int g  = (HT == 4) ? (t0 >> 2) : t0;
    const int rb = g * 8 + x;                     // row band
    const int row0 = rb * 128, col0 = by * 128;
    if (row0 >= M) return;

    f32x4 acc[4][4];
    #pragma unroll
    for (int i = 0; i < 4; i++)
        #pragma unroll
        for (int j = 0; j < 4; j++)
            acc[i][j] = (f32x4){0.f, 0.f, 0.f, 0.f};

    const int ldm = tid >> 3;                               // row 0..31 within 32-row group
    const int kpart = (((tid & 7) ^ ((tid >> 3) & 7)) * 8); // swizzled source chunk (shorts)
    const int fr = lane & 15;
    const int quad = lane >> 4;

    for (int k0 = 0; k0 < K; k0 += 64) {
        __syncthreads();
        #pragma unroll
        for (int i = 0; i < 4; i++) {
            int gr = row0 + i * 32 + ldm; if (gr >= M) gr = M - 1;
            gload_lds16(A + (size_t)gr * K + k0 + kpart, &As[i * 2048 + tid * 8]);
            int n = col0 + i * 32 + ldm;
            gload_lds16(Wt + (size_t)n * K + k0 + kpart, &Bs[i * 2048 + tid * 8]);
        }
        __syncthreads();
        #pragma unroll
        for (int s = 0; s < 2; s++) {
            const int slot8 = (((s << 2) + quad) ^ (fr & 7)) * 8;
            short8 a[4], b[4];
            #pragma unroll
            for (int tt = 0; tt < 4; tt++) {
                a[tt] = *(const short8*)&As[(wm * 64 + tt * 16 + fr) * 64 + slot8];
                b[tt] = *(const short8*)&Bs[(wn * 64 + tt * 16 + fr) * 64 + slot8];
            }
            #pragma unroll
            for (int mi = 0; mi < 4; mi++)
                #pragma unroll
                for (int ni = 0; ni < 4; ni++)
                    acc[mi][ni] = __builtin_amdgcn_mfma_f32_16x16x32_bf16(
                        a[mi], b[ni], acc[mi][ni], 0, 0, 0);
        }
    }

    // C store. C/D layout: col = lane&15, row = quad*4 + reg
    const int rbase = row0 + wm * 64 + quad * 4;
    const int cbase = col0 + wn * 64 + fr;
    #pragma unroll
    for (int mi = 0; mi < 4; mi++) {
        #pragma unroll
        for (int reg = 0; reg < 4; reg++) {
            int r = rbase + mi * 16 + reg;
            if (r < M) {
                #pragma unroll
                for (int ni = 0; ni < 4; ni++)
                    C[(size_t)r * Nc + cbase + ni * 16] = f2bf(acc[mi][ni][reg]);
            }
        }
    }

    // fused scores: channel (within head) for this lane = wn*64 + ni*16 + fr
    float asv[4], adv[4];
    #pragma unroll
    for (int ni = 0; ni < 4; ni++) {
        int c = by * 128 + wn * 64 + ni * 16 + fr;
        asv[ni] = a_s[c];
        adv[ni] = a_d[c];
    }
    float ps[4][4], pd[4][4];
    #pragma unroll
    for (int mi = 0; mi < 4; mi++)
        #pragma unroll
        for (int reg = 0; reg < 4; reg++) {
            float t = 0.f, u = 0.f;
            #pragma unroll
            for (int ni = 0; ni < 4; ni++) {
                t += acc[mi][ni][reg] * asv[ni];
                u += acc[mi][ni][reg] * adv[ni];
            }
            ps[mi][reg] = t;
            pd[mi][reg] = u;
        }
    #pragma unroll
    for (int off = 1; off <= 8; off <<= 1)
        #pragma unroll
        for (int mi = 0; mi < 4; mi++)
            #pragma unroll
            for (int reg = 0; reg < 4; reg++) {
                ps[mi][reg] += __shfl_xor(ps[mi][reg], off, 64);
                pd[mi][reg] += __shfl_xor(pd[mi][reg], off, 64);
            }
    float oS = 0.f, oD = 0.f;
    #pragma unroll
    for (int mi = 0; mi < 4; mi++)
        #pragma unroll
        for (int reg = 0; reg < 4; reg++)
            if (fr == mi * 4 + reg) { oS = ps[mi][reg]; oD = pd[mi][reg]; }
    int rw = rbase + (fr >> 2) * 16 + (fr & 3);
    if (rw < M) {
        s2[(size_t)rw * (2 * H) + wn * H + by] = oS;
        d2[(size_t)rw * (2 * H) + wn * H + by] = oD;
    }
}

// ---------------- edge weights: wgt[pos][h] = exp(leaky(s[col]+d[dst])) ----------------

template <int H>
__global__ void edge_weights(const int* __restrict__ col, const int* __restrict__ dstn,
                             const float* __restrict__ s2, const float* __restrict__ d2,
                             float* __restrict__ wgt, int P) {
    int p = blockIdx.x * blockDim.x + threadIdx.x;
    if (p >= P) return;
    int sn = col[p], dn = dstn[p];
    if (H == 4) {
        float4 sa = *(const float4*)&s2[sn * 8];
        float4 sb = *(const float4*)&s2[sn * 8 + 4];
        float4 da = *(const float4*)&d2[dn * 8];
        float4 db = *(const float4*)&d2[dn * 8 + 4];
        float4 o;
        float e;
        e = sa.x + sb.x + da.x + db.x; e = e > 0.f ? e : NEG_SLOPE * e; o.x = __expf(e);
        e = sa.y + sb.y + da.y + db.y; e = e > 0.f ? e : NEG_SLOPE * e; o.y = __expf(e);
        e = sa.z + sb.z + da.z + db.z; e = e > 0.f ? e : NEG_SLOPE * e; o.z = __expf(e);
        e = sa.w + sb.w + da.w + db.w; e = e > 0.f ? e : NEG_SLOPE * e; o.w = __expf(e);
        *(float4*)&wgt[p * 4] = o;
    } else {
        float e = s2[sn * 2] + s2[sn * 2 + 1] + d2[dn * 2] + d2[dn * 2 + 1];
        e = e > 0.f ? e : NEG_SLOPE * e;
        wgt[p] = __expf(e);
    }
}

// ---------------- H=4 aggregation: wave per node, cnt-guarded unroll 8 ----------------
// guard is wave-uniform -> scalar branch skips dead loads AND dead FMAs (no clamp dups).

__global__ void gat_agg_h4(const unsigned short* __restrict__ h, const float* __restrict__ wgt,
                           const int* __restrict__ row_start, const int* __restrict__ col,
                           const float* __restrict__ bias,
                           const float* __restrict__ gam, const float* __restrict__ beta,
                           const float* __restrict__ rm, const float* __restrict__ rv,
                           unsigned short* __restrict__ out, int N) {
    int lane = threadIdx.x & 63;
    int wv = threadIdx.x >> 6;
    int n = blockIdx.x * 4 + wv;
    if (n >= N) return;
    int beg = row_start[n], end = row_start[n + 1];
    int hh = lane >> 4;
    int ch0 = lane * 8;

    float acc[8] = {0.f, 0.f, 0.f, 0.f, 0.f, 0.f, 0.f, 0.f};
    float denom = 0.f;

    for (int i = beg; i < end; i += 8) {
        int cnt = end - i; cnt = cnt > 8 ? 8 : cnt;   // wave-uniform
        uint4 raw[8]; float w[8];
        #pragma unroll
        for (int u = 0; u < 8; u++) {
            if (u < cnt) {
                int e = i + u;
                int sn = col[e];
                w[u] = wgt[e * 4 + hh];
                raw[u] = *(const uint4*)&h[(size_t)sn * 512 + ch0];
            }
        }
        #pragma unroll
        for (int u = 0; u < 8; u++) {
            if (u < cnt) {
                denom += w[u];
                acc[0] += w[u] * bf2f((unsigned short)(raw[u].x & 0xffff));
                acc[1] += w[u] * bf2f((unsigned short)(raw[u].x >> 16));
                acc[2] += w[u] * bf2f((unsigned short)(raw[u].y & 0xffff));
                acc[3] += w[u] * bf2f((unsigned short)(raw[u].y >> 16));
                acc[4] += w[u] * bf2f((unsigned short)(raw[u].z & 0xffff));
                acc[5] += w[u] * bf2f((unsigned short)(raw[u].z >> 16));
                acc[6] += w[u] * bf2f((unsigned short)(raw[u].w & 0xffff));
                acc[7] += w[u] * bf2f((unsigned short)(raw[u].w >> 16));
            }
        }
    }
    float inv = 1.f / denom;
    float v[8];
    #pragma unroll
    for (int c = 0; c < 8; c++) {
        int ch = ch0 + c;
        float t = acc[c] * inv + bias[ch];
        t = (t - rm[ch]) * (gam[ch] * rsqrtf(rv[ch] + BN_EPS)) + beta[ch];
        v[c] = t > 0.f ? t : expf(t) - 1.f;
    }
    uint4 p;
    p.x = (unsigned int)f2bf(v[0]) | ((unsigned int)f2bf(v[1]) << 16);
    p.y = (unsigned int)f2bf(v[2]) | ((unsigned int)f2bf(v[3]) << 16);
    p.z = (unsigned int)f2bf(v[4]) | ((unsigned int)f2bf(v[5]) << 16);
    p.w = (unsigned int)f2bf(v[6]) | ((unsigned int)f2bf(v[7]) << 16);
    *(uint4*)&out[(size_t)n * 512 + ch0] = p;
}

// ---------------- H=1 aggregation + BN + ELU + fused classifier -> d_out[N,2] ----------------
// tail handled by per-lane predication (exec-masked loads, w=0 for dead slots).

__global__ void gat_agg_h1_cls(const unsigned short* __restrict__ h, const float* __restrict__ wgt,
                               const int* __restrict__ row_start, const int* __restrict__ col,
                               const float* __restrict__ bias,
                               const float* __restrict__ gam, const float* __restrict__ beta,
                               const float* __restrict__ rm, const float* __restrict__ rv,
                               const float* __restrict__ Wc, const float* __restrict__ bc,
                               float* __restrict__ out, int N) {
    int lane = threadIdx.x & 63;
    int wv = threadIdx.x >> 6;
    int n = blockIdx.x * 4 + wv;
    if (n >= N) return;
    int beg = row_start[n], end = row_start[n + 1];
    int q = lane >> 4;
    int fl = lane & 15;
    const size_t hoff = fl * 8;

    float acc[8] = {0.f, 0.f, 0.f, 0.f, 0.f, 0.f, 0.f, 0.f};
    float denom = 0.f;

    for (int i = beg; i < end; i += 16) {
        uint4 raw[4]; float w[4];
        #pragma unroll
        for (int u = 0; u < 4; u++) {
            int e0 = i + u * 4 + q;
            w[u] = 0.f;
            raw[u] = make_uint4(0u, 0u, 0u, 0u);
            if (e0 < end) {
                int sn = col[e0];
                w[u] = wgt[e0];
                raw[u] = *(const uint4*)&h[(size_t)sn * 128 + hoff];
            }
        }
        #pragma unroll
        for (int u = 0; u < 4; u++) {
            denom += w[u];
            acc[0] += w[u] * bf2f((unsigned short)(raw[u].x & 0xffff));
            acc[1] += w[u] * bf2f((unsigned short)(raw[u].x >> 16));
            acc[2] += w[u] * bf2f((unsigned short)(raw[u].y & 0xffff));
            acc[3] += w[u] * bf2f((unsigned short)(raw[u].y >> 16));
            acc[4] += w[u] * bf2f((unsigned short)(raw[u].z & 0xffff));
            acc[5] += w[u] * bf2f((unsigned short)(raw[u].z >> 16));
            acc[6] += w[u] * bf2f((unsigned short)(raw[u].w & 0xffff));
            acc[7] += w[u] * bf2f((unsigned short)(raw[u].w >> 16));
        }
    }
    #pragma unroll
    for (int c = 0; c < 8; c++) {
        acc[c] += __shfl_xor(acc[c], 16, 64);
        acc[c] += __shfl_xor(acc[c], 32, 64);
    }
    denom += __shfl_xor(denom, 16, 64);
    denom += __shfl_xor(denom, 32, 64);

    if (q == 0) {
        float inv = 1.f / denom;
        int ch0 = fl * 8;
        float p0 = 0.f, p1 = 0.f;
        #pragma unroll
        for (int c = 0; c < 8; c++) {
            int ch = ch0 + c;
            float t = acc[c] * inv + bias[ch];
            t = (t - rm[ch]) * (gam[ch] * rsqrtf(rv[ch] + BN_EPS)) + beta[ch];
            t = t > 0.f ? t : expf(t) - 1.f;
            p0 += t * Wc[ch * 2 + 0];
            p1 += t * Wc[ch * 2 + 1];
        }
        #pragma unroll
        for (int off = 8; off >= 1; off >>= 1) {
            p0 += __shfl_xor(p0, off, 64);
            p1 += __shfl_xor(p1, off, 64);
        }
        if (fl == 0) {
            out[n * 2 + 0] = p0 + bc[0];
            out[n * 2 + 1] = p1 + bc[1];
        }
    }
}

// ---------------- launch ----------------

extern "C" void kernel_launch(void* const* d_in, const int* in_sizes, int n_in,
                              void* d_out, int out_size, void* d_ws, size_t ws_size,
                              hipStream_t stream) {
    const float* x   = (const float*)d_in[0];
    const int*   ei  = (const int*)d_in[1];
    const float* W1  = (const float*)d_in[2];
    const float* a1s = (const float*)d_in[3];
    const float* a1d = (const float*)d_in[4];
    const float* b1  = (const float*)d_in[5];
    const float* gm1 = (const float*)d_in[6];
    const float* be1 = (const float*)d_in[7];
    const float* rm1 = (const float*)d_in[8];
    const float* rv1 = (const float*)d_in[9];
    const float* W2  = (const float*)d_in[10];
    const float* a2s = (const float*)d_in[11];
    const float* a2d = (const float*)d_in[12];
    const float* b2  = (const float*)d_in[13];
    const float* gm2 = (const float*)d_in[14];
    const float* be2 = (const float*)d_in[15];
    const float* rm2 = (const float*)d_in[16];
    const float* rv2 = (const float*)d_in[17];
    const float* W3  = (const float*)d_in[18];
    const float* a3s = (const float*)d_in[19];
    const float* a3d = (const float*)d_in[20];
    const float* b3  = (const float*)d_in[21];
    const float* gm3 = (const float*)d_in[22];
    const float* be3 = (const float*)d_in[23];
    const float* rm3 = (const float*)d_in[24];
    const float* rv3 = (const float*)d_in[25];
    const float* Wc  = (const float*)d_in[26];
    const float* bc  = (const float*)d_in[27];

    int N = in_sizes[0] / IN_F;       // 50000
    int E = in_sizes[1] / 2;          // 400000
    int P = E + N;                    // CSR slots
    const int* srcA = ei;
    const int* dstA = ei + E;

    unsigned short* xb   = (unsigned short*)d_ws;        // N*768 bf16
    unsigned short* hbuf = xb + (size_t)N * 768;         // N*512 bf16
    unsigned short* gbuf = hbuf + (size_t)N * 512;       // N*512 bf16
    float* s2   = (float*)(gbuf + (size_t)N * 512);      // N*8 (two halves x 4 heads)
    float* d2   = s2 + (size_t)N * 8;                    // N*8
    float* wgt  = d2 + (size_t)N * 8;                    // P*4
    unsigned short* Wt1 = (unsigned short*)(wgt + (size_t)P * 4);  // 512*768
    unsigned short* Wt2 = Wt1 + 512 * 768;               // 512*512
    unsigned short* Wt3 = Wt2 + 512 * 512;               // 128*512
    int* count     = (int*)(Wt3 + 128 * 512);
    int* cursor    = count + N;
    int* row_start = cursor + N;
    int* col       = row_start + N + 1;                  // P
    int* dstn      = col + P;                            // P

    // CSR (rebuild every call: ws re-poisoned)
    init_counts<<<(N + 255) / 256, 256, 0, stream>>>(count, cursor, N);
    count_edges<<<(E + 255) / 256, 256, 0, stream>>>(dstA, E, count);
    scan_counts<<<1, 1024, 0, stream>>>(count, row_start, N);
    scatter_edges<<<(E + N + 255) / 256, 256, 0, stream>>>(srcA, dstA, E, N, row_start,
                                                           cursor, col, dstn);
    // casts (one launch)
    long xq = (long)N * IN_F / 4;
    long ctot = xq + 768 * 512 + 512 * 512 + 512 * 128;
    cast_all<<<(int)((ctot + 255) / 256), 256, 0, stream>>>(x, xb, xq, W1, W2, W3,
                                                            Wt1, Wt2, Wt3);

    int Mb = (N + 127) / 128;          // 391
    int MbP = (Mb + 7) & ~7;           // 392, multiple of 8 for XCD mapping
    int Nb4 = (N + 3) / 4;

    // Layer 1
    gemm_bf16<<<4 * MbP, 256, 0, stream>>>(xb, Wt1, hbuf, a1s, a1d, s2, d2, N, 512, 768, 4);
    edge_weights<4><<<(P + 255) / 256, 256, 0, stream>>>(col, dstn, s2, d2, wgt, P);
    gat_agg_h4<<<Nb4, 256, 0, stream>>>(hbuf, wgt, row_start, col,
                                        b1, gm1, be1, rm1, rv1, gbuf, N);
    // Layer 2
    gemm_bf16<<<4 * MbP, 256, 0, stream>>>(gbuf, Wt2, hbuf, a2s, a2d, s2, d2, N, 512, 512, 4);
    edge_weights<4><<<(P + 255) / 256, 256, 0, stream>>>(col, dstn, s2, d2, wgt, P);
    gat_agg_h4<<<Nb4, 256, 0, stream>>>(hbuf, wgt, row_start, col,
                                        b2, gm2, be2, rm2, rv2, gbuf, N);
    // Layer 3 (1 head) + fused classifier
    gemm_bf16<<<MbP, 256, 0, stream>>>(gbuf, Wt3, hbuf, a3s, a3d, s2, d2, N, 128, 512, 1);
    edge_weights<1><<<(P + 255) / 256, 256, 0, stream>>>(col, dstn, s2, d2, wgt, P);
    gat_agg_h1_cls<<<Nb4, 256, 0, stream>>>(hbuf, wgt, row_start, col,
                                            b3, gm3, be3, rm3, rv3, Wc, bc, (float*)d_out, N);
}